// Round 16
// baseline (694.430 us; speedup 1.0000x reference)
//
#include <hip/hip_runtime.h>

typedef __attribute__((ext_vector_type(4))) float f32x4;
typedef __attribute__((ext_vector_type(8))) short bf16x8;
typedef __attribute__((ext_vector_type(4))) unsigned short u16x4;
typedef __attribute__((ext_vector_type(2))) unsigned int u32x2;
typedef __attribute__((ext_vector_type(2))) _Float16 h16x2;
typedef unsigned short u16;

#if defined(__has_builtin)
#if __has_builtin(__builtin_amdgcn_fdot2)
#define HAS_FDOT2 1
#endif
#endif

// Static device intermediates (BSS; fully rewritten every launch).
__device__ static u16   g_xh[(size_t)50176 * 768];     // bf16(x)            77 MB
__device__ static u16   g_wqkvh[(size_t)2304 * 768];   // bf16(w_qkv)       3.5 MB
__device__ static u16   g_wprojh[(size_t)768 * 768];   // bf16(w_proj)      1.2 MB
__device__ static u16   g_qkv[(size_t)50176 * 2304];   // qkv bf16/f16      231 MB
__device__ static u16   g_g1[(size_t)48 * 784 * 256];  // conv1 out bf16     19 MB
__device__ static u16   g_g2[(size_t)48 * 196 * 256];  // conv2 out bf16    4.8 MB
__device__ static u16   g_fh[(size_t)50176 * 768];     // fused bf16         77 MB
__device__ static unsigned g_wt1[18 * 256];            // conv1 w f16-pairs [18][256]
__device__ static unsigned g_wt2[18 * 256];            // conv2 w f16-pairs [18][256]

static __device__ __forceinline__ u16 f2bf(float x){
  unsigned u = __float_as_uint(x);
  u += 0x7fffu + ((u >> 16) & 1u);
  return (u16)(u >> 16);
}
static __device__ __forceinline__ float bf2f(u16 h){
  return __uint_as_float(((unsigned)h) << 16);
}
static __device__ __forceinline__ u16 f2h(float x){
  _Float16 h = (_Float16)x;
  u16 b; __builtin_memcpy(&b, &h, 2);
  return b;
}
static __device__ __forceinline__ h16x2 as_h2(unsigned u){
  h16x2 v; __builtin_memcpy(&v, &u, 4); return v;
}
static __device__ __forceinline__ float dot2(unsigned a, unsigned b, float c){
#ifdef HAS_FDOT2
  return __builtin_amdgcn_fdot2(as_h2(a), as_h2(b), c, false);
#else
  const h16x2 ha = as_h2(a), hb = as_h2(b);
  return c + (float)ha[0] * (float)hb[0] + (float)ha[1] * (float)hb[1];
#endif
}

// Merged f32 -> bf16 (RNE) for three arrays, vectorized x4, grid-stride.
__global__ __launch_bounds__(256)
void cvt_bf16_3(const float* __restrict__ i0, u16* __restrict__ o0, int n0,
                const float* __restrict__ i1, u16* __restrict__ o1, int n1,
                const float* __restrict__ i2, u16* __restrict__ o2, int n2)
{
  const int total = n0 + n1 + n2;
  int i = blockIdx.x * blockDim.x + threadIdx.x;
  const int stride = gridDim.x * blockDim.x;
  for (; i < total; i += stride) {
    const float* in; u16* out; int j = i;
    if (j < n0)           { in = i0; out = o0; }
    else if (j < n0 + n1) { in = i1; out = o1; j -= n0; }
    else                  { in = i2; out = o2; j -= n0 + n1; }
    const f32x4 v = ((const f32x4*)in)[j];
    u16x4 o;
    #pragma unroll
    for (int k = 0; k < 4; k++) o[k] = f2bf(v[k]);
    ((u16x4*)out)[j] = o;
  }
}

// Conv weight prep: [256ch][4ic][9tap] f32 -> [tap*2+k][256ch] packed f16
// pairs (ic 2k, 2k+1) for v_dot2.
__global__ __launch_bounds__(256)
void prep_wt(const float* __restrict__ w1, unsigned* __restrict__ wt1,
             const float* __restrict__ w2, unsigned* __restrict__ wt2)
{
  const int i = blockIdx.x * 256 + threadIdx.x;
  if (i < 4608) {
    const int ch = i & 255, t2 = i >> 8;     // t2 = tp*2+k, 0..17
    const int tp = t2 >> 1, k = t2 & 1;
    const int i0 = ch * 36 + (2 * k) * 9 + tp;
    const int i1 = ch * 36 + (2 * k + 1) * 9 + tp;
    wt1[t2 * 256 + ch] = (unsigned)f2h(w1[i0]) | ((unsigned)f2h(w1[i1]) << 16);
    wt2[t2 * 256 + ch] = (unsigned)f2h(w2[i0]) | ((unsigned)f2h(w2[i1]) << 16);
  }
}

// ---------------------------------------------------------------------------
// 128x128-tile GEMM, 4 waves (2x2), BK=32, 4 LDS buffers (64KB -> 2 blocks/CU
// of cross-block TLP), lead-2 counted-vmcnt pipeline (R6 discipline: vmcnt(8),
// ONE barrier/step, never drained in-loop).  C = A * B^T (+bias).
// Race ledger (R6-identical): STAGE(t+2) writes buf (t+2)&3 = (t-2)&3, whose
// reads [COMPUTE(t-2)] precede every wave's arrival at the iter-(t-1) barrier,
// which every wave passes before issuing STAGE(t+2).
// LDS layout + staging inverse-swizzle + epilogue mapping: R8-refverified.
// CF16: write cols with (col%768)>=256 as f16 (conv input channels).
// ---------------------------------------------------------------------------
template<bool BIAS, bool CF16, typename OUT_T>
__global__ __launch_bounds__(256)
void gemm128(const u16* __restrict__ A0, const u16* __restrict__ Bw,
             const float* __restrict__ bias, OUT_T* __restrict__ C,
             int N, int K, int GX)
{
  __shared__ __align__(16) char ldsb[4 * 16384];   // 4 buf x (A 8K + B 8K)
  const int tid = threadIdx.x;
  const int lane = tid & 63;
  const int w = tid >> 6;
  const int wm = w >> 1, wn = w & 1;
  const int l15 = lane & 15, l4 = lane >> 4;

  // T1 bijective XCD swizzle (m204).
  const int nwg = gridDim.x;
  const int bid = blockIdx.x;
  const int q8 = nwg >> 3, r8 = nwg & 7;
  const int xcd = bid & 7, lid = bid >> 3;
  const int swz = (xcd < r8 ? xcd * (q8 + 1) : r8 * (q8 + 1) + (xcd - r8) * q8) + lid;
  const int bn = swz % GX;
  const int bm = swz / GX;

  // ---- staging source precompute (inverse swizzle; slots tid and tid+256) --
  const int pr0 = tid >> 3, sp0 = tid & 7;
  const int tt0 = sp0 ^ (pr0 & 7);
  const int row0 = pr0 * 2 + (tt0 >> 2), col0 = (tt0 & 3) * 8;
  const int s1 = tid + 256;
  const int pr1 = s1 >> 3, sp1 = s1 & 7;
  const int tt1 = sp1 ^ (pr1 & 7);
  const int row1 = pr1 * 2 + (tt1 >> 2), col1 = (tt1 & 3) * 8;

  const u16* pa0 = A0 + (size_t)(bm * 128 + row0) * K + col0;
  const u16* pa1 = A0 + (size_t)(bm * 128 + row1) * K + col1;
  const u16* pb0 = Bw + (size_t)(bn * 128 + row0) * K + col0;
  const u16* pb1 = Bw + (size_t)(bn * 128 + row1) * K + col1;

  #define GLDS(srcp, ldsoff) __builtin_amdgcn_global_load_lds( \
      (__attribute__((address_space(1))) const void*)(srcp),   \
      (__attribute__((address_space(3))) void*)(ldsb + (ldsoff)), 16, 0, 0)

  auto STAGE = [&](int s) {
    const int base = (s & 3) << 14;
    const int ko = s * 32;
    GLDS(pa0 + ko, base + tid * 16);
    GLDS(pa1 + ko, base + 4096 + tid * 16);
    GLDS(pb0 + ko, base + 8192 + tid * 16);
    GLDS(pb1 + ko, base + 12288 + tid * 16);
  };

  f32x4 acc[4][4];
  #pragma unroll
  for (int i = 0; i < 4; i++)
    #pragma unroll
    for (int j = 0; j < 4; j++) acc[i][j] = (f32x4)0.f;

  auto COMPUTE = [&](int t) {
    const char* base = ldsb + ((t & 3) << 14);
    bf16x8 afr[4], bfr[4];
    #pragma unroll
    for (int mi = 0; mi < 4; mi++) {
      const int r = wm * 64 + mi * 16 + l15;
      const int pr = r >> 1;
      const int p = (((r & 1) << 2) + l4) ^ (pr & 7);
      afr[mi] = *(const bf16x8*)(base + pr * 128 + p * 16);
    }
    #pragma unroll
    for (int ni = 0; ni < 4; ni++) {
      const int r = wn * 64 + ni * 16 + l15;
      const int pr = r >> 1;
      const int p = (((r & 1) << 2) + l4) ^ (pr & 7);
      bfr[ni] = *(const bf16x8*)(base + 8192 + pr * 128 + p * 16);
    }
    __builtin_amdgcn_s_setprio(1);
    #pragma unroll
    for (int mi = 0; mi < 4; mi++)
      #pragma unroll
      for (int ni = 0; ni < 4; ni++)
        acc[mi][ni] = __builtin_amdgcn_mfma_f32_16x16x32_bf16(afr[mi], bfr[ni], acc[mi][ni], 0, 0, 0);
    __builtin_amdgcn_s_setprio(0);
  };

  const int T = K >> 5;   // K/32 steps
  STAGE(0);
  STAGE(1);
  for (int t = 0; t < T - 2; ++t) {
    STAGE(t + 2);
    asm volatile("s_waitcnt vmcnt(8)" ::: "memory");
    __builtin_amdgcn_sched_barrier(0);
    __builtin_amdgcn_s_barrier();
    __builtin_amdgcn_sched_barrier(0);
    COMPUTE(t);
  }
  asm volatile("s_waitcnt vmcnt(4)" ::: "memory");
  __builtin_amdgcn_sched_barrier(0);
  __builtin_amdgcn_s_barrier();
  __builtin_amdgcn_sched_barrier(0);
  COMPUTE(T - 2);
  asm volatile("s_waitcnt vmcnt(0)" ::: "memory");
  __builtin_amdgcn_sched_barrier(0);
  __builtin_amdgcn_s_barrier();
  __builtin_amdgcn_sched_barrier(0);
  COMPUTE(T - 1);
  #undef GLDS

  // ---- epilogue (R8-verified mapping) ----
  #pragma unroll
  for (int mi = 0; mi < 4; mi++)
    #pragma unroll
    for (int ni = 0; ni < 4; ni++) {
      const int col = bn * 128 + wn * 64 + ni * 16 + l15;
      const float bv = BIAS ? bias[col] : 0.f;
      bool asf16 = false;
      if constexpr (CF16) {
        int cm = col;
        cm -= (cm >= 1536) ? 1536 : ((cm >= 768) ? 768 : 0);
        asf16 = (cm >= 256);
      }
      #pragma unroll
      for (int reg = 0; reg < 4; reg++) {
        const int row = bm * 128 + wm * 64 + mi * 16 + (l4 << 2) + reg;
        const float val = acc[mi][ni][reg] + bv;
        if constexpr (sizeof(OUT_T) == 2) {
          C[(size_t)row * N + col] = (OUT_T)(asf16 ? f2h(val) : f2bf(val));
        } else {
          C[(size_t)row * N + col] = val;
        }
      }
    }
}

// ---------------------------------------------------------------------------
// f16-dot2 grouped conv3x3 + bias + 2x2 maxpool -> bf16 (R15-verified).
// ---------------------------------------------------------------------------
template<int S>
__global__ __launch_bounds__(256, 5)
void conv_s(const u16* __restrict__ qkv, const unsigned* __restrict__ wt,
            const float* __restrict__ bsrc, u16* __restrict__ gout,
            int chan0, int Pout)
{
  const int ch = threadIdx.x;          // output channel 0..255
  const int g = ch >> 2;
  const int bt = blockIdx.x;
  const int b = bt / 3, t = bt - b * 3;
  const int blk = blockIdx.y;          // pooled pixel index
  const int y = blk / Pout, x0 = blk - y * Pout;

  // 18 packed f16 weight pairs -> registers (lane-coalesced loads).
  unsigned wp[18];
  #pragma unroll
  for (int j = 0; j < 18; j++) wp[j] = wt[j * 256 + ch];
  const float bv = bsrc[ch];

  const int R0 = 2 * S * y - S;
  const int C0 = 2 * S * x0 - S;
  const size_t basech = (size_t)t * 768 + chan0 + g * 4;
  const u16* const srcb = qkv + (size_t)b * 3136 * 2304 + basech;

  // pixel (i,c) -> two packed f16 pairs (4 input channels)
  u32x2 praw[4][4];
  const bool interior = (R0 >= 0) & (R0 + 3 * S < 56) & (C0 >= 0) & (C0 + 3 * S < 56);
  if (interior) {
    #pragma unroll
    for (int i = 0; i < 4; i++)
      #pragma unroll
      for (int c = 0; c < 4; c++)
        praw[i][c] = *(const u32x2*)&srcb[(size_t)((R0 + i * S) * 56 + C0 + c * S) * 2304];
  } else {
    #pragma unroll
    for (int i = 0; i < 4; i++) {
      const int iy = R0 + i * S;
      const int iyc = iy < 0 ? 0 : (iy > 55 ? 55 : iy);
      const bool rok = (iy >= 0) & (iy < 56);
      #pragma unroll
      for (int c = 0; c < 4; c++) {
        const int ix = C0 + c * S;
        const int ixc = ix < 0 ? 0 : (ix > 55 ? 55 : ix);
        u32x2 r2 = *(const u32x2*)&srcb[(size_t)(iyc * 56 + ixc) * 2304];
        const bool ok = rok & (ix >= 0) & (ix < 56);
        r2[0] = ok ? r2[0] : 0u;
        r2[1] = ok ? r2[1] : 0u;
        praw[i][c] = r2;
      }
    }
  }

  float acc[2][2];
  #pragma unroll
  for (int dy = 0; dy < 2; dy++)
    #pragma unroll
    for (int dx = 0; dx < 2; dx++) acc[dy][dx] = bv;

  #pragma unroll
  for (int i = 0; i < 4; i++)
    #pragma unroll
    for (int c = 0; c < 4; c++) {
      const u32x2 p2 = praw[i][c];
      #pragma unroll
      for (int dy = 0; dy < 2; dy++) {
        const int ky = i - dy;
        if (ky < 0 || ky > 2) continue;
        #pragma unroll
        for (int dx = 0; dx < 2; dx++) {
          const int kx = c - dx;
          if (kx < 0 || kx > 2) continue;
          const int tp = ky * 3 + kx;
          acc[dy][dx] = dot2(p2[0], wp[tp * 2 + 0], acc[dy][dx]);
          acc[dy][dx] = dot2(p2[1], wp[tp * 2 + 1], acc[dy][dx]);
        }
      }
    }

  const float best = fmaxf(fmaxf(acc[0][0], acc[0][1]),
                           fmaxf(acc[1][0], acc[1][1]));
  gout[((size_t)bt * (Pout * Pout) + blk) * 256 + ch] = f2bf(best);
}

// ---------------------------------------------------------------------------
// MFMA windowed attention, ALL scales in one launch. One WAVE per
// (b, region, head); 4 waves/block.
// ---------------------------------------------------------------------------
template<int SRC>
static __device__ __forceinline__
void attn_body(const u16* __restrict__ src, u16* __restrict__ fh,
               int side, int Hs, int head_base, int rep,
               int unit, int lane, char* vb, char* pb)
{
  const int nreg = side * side;
  const int h = unit & 3; unit >>= 2;
  const int r = unit % nreg;
  const int b = unit / nreg;
  const int hr = r / side, wr = r - hr * side;
  const int l15 = lane & 15, l4 = lane >> 4;

  auto gidx = [&](int t, int pp, int c) -> size_t {
    const int py = pp / 7, px = pp - py * 7;
    const int yy = hr * 7 + py, xx = wr * 7 + px;
    if (SRC == 0) return ((size_t)(b * 3136 + yy * 56 + xx)) * 2304 + (size_t)(t * 768 + h * 64 + c);
    else          return ((size_t)(b * 3 + t)) * ((size_t)Hs * Hs * 256) + (size_t)(yy * Hs + xx) * 256 + h * 64 + c;
  };

  // ---- stage V (t=2), rows clamped; swizzle byte ^= ((q>>3)&3)<<5 ----
  for (int i = lane; i < 1024; i += 64) {
    const int q = i >> 4, dc = i & 15;
    const int qs = q > 48 ? 48 : q;
    const u16x4 v4 = *(const u16x4*)&src[gidx(2, qs, dc * 4)];
    *(u16x4*)(vb + ((q * 128 + dc * 8) ^ (((q >> 3) & 3) << 5))) = v4;
  }

  // ---- QK^T ----
  f32x4 s[4][4];
  #pragma unroll
  for (int i = 0; i < 4; i++)
    #pragma unroll
    for (int j = 0; j < 4; j++) s[i][j] = (f32x4)0.f;

  bf16x8 bk[4][2];
  #pragma unroll
  for (int ni = 0; ni < 4; ni++) {
    const int q = ni * 16 + l15;
    const int qs = q > 48 ? 48 : q;
    #pragma unroll
    for (int ks = 0; ks < 2; ks++)
      bk[ni][ks] = *(const bf16x8*)&src[gidx(1, qs, ks * 32 + l4 * 8)];
  }
  #pragma unroll
  for (int mi = 0; mi < 4; mi++) {
    const int p = mi * 16 + l15;
    const int ps = p > 48 ? 48 : p;
    const bf16x8 a0 = *(const bf16x8*)&src[gidx(0, ps, l4 * 8)];
    const bf16x8 a1 = *(const bf16x8*)&src[gidx(0, ps, 32 + l4 * 8)];
    #pragma unroll
    for (int ni = 0; ni < 4; ni++) {
      s[mi][ni] = __builtin_amdgcn_mfma_f32_16x16x32_bf16(a0, bk[ni][0], s[mi][ni], 0, 0, 0);
      s[mi][ni] = __builtin_amdgcn_mfma_f32_16x16x32_bf16(a1, bk[ni][1], s[mi][ni], 0, 0, 0);
    }
  }

  // ---- mask cols q>=49, in-register softmax (unnormalized P) ----
  #pragma unroll
  for (int ni = 0; ni < 4; ni++) {
    const bool bad = (ni * 16 + l15) > 48;
    #pragma unroll
    for (int mi = 0; mi < 4; mi++)
      #pragma unroll
      for (int reg = 0; reg < 4; reg++)
        s[mi][ni][reg] = bad ? -1e30f : s[mi][ni][reg];
  }

  float inv[4][4];
  #pragma unroll
  for (int mi = 0; mi < 4; mi++)
    #pragma unroll
    for (int reg = 0; reg < 4; reg++) {
      float m = fmaxf(fmaxf(s[mi][0][reg], s[mi][1][reg]), fmaxf(s[mi][2][reg], s[mi][3][reg]));
      m = fmaxf(m, __shfl_xor(m, 1));
      m = fmaxf(m, __shfl_xor(m, 2));
      m = fmaxf(m, __shfl_xor(m, 4));
      m = fmaxf(m, __shfl_xor(m, 8));
      float partial = 0.f;
      #pragma unroll
      for (int ni = 0; ni < 4; ni++) {
        const float e = __expf((s[mi][ni][reg] - m) * 0.125f);
        s[mi][ni][reg] = e;
        partial += e;
      }
      partial += __shfl_xor(partial, 1);
      partial += __shfl_xor(partial, 2);
      partial += __shfl_xor(partial, 4);
      partial += __shfl_xor(partial, 8);
      inv[mi][reg] = 1.f / partial;
    }

  // ---- P -> LDS (bf16, XOR-swizzled rows) ----
  #pragma unroll
  for (int mi = 0; mi < 4; mi++)
    #pragma unroll
    for (int ni = 0; ni < 4; ni++)
      #pragma unroll
      for (int reg = 0; reg < 4; reg++) {
        const int row = mi * 16 + l4 * 4 + reg;
        const int col = ni * 16 + l15;
        *(u16*)(pb + ((row * 128 + col * 2) ^ ((row & 7) << 4))) = f2bf(s[mi][ni][reg]);
      }
  __syncthreads();

  // ---- PV ----
  f32x4 o[4][4];
  #pragma unroll
  for (int i = 0; i < 4; i++)
    #pragma unroll
    for (int j = 0; j < 4; j++) o[i][j] = (f32x4)0.f;

  #pragma unroll
  for (int ks = 0; ks < 2; ks++) {
    bf16x8 bv[4];
    #pragma unroll
    for (int ni = 0; ni < 4; ni++)
      #pragma unroll
      for (int j = 0; j < 8; j++) {
        const int q = ks * 32 + l4 * 8 + j;
        bv[ni][j] = *(const short*)(vb + ((q * 128 + (ni * 16 + l15) * 2) ^ (((q >> 3) & 3) << 5)));
      }
    #pragma unroll
    for (int mi = 0; mi < 4; mi++) {
      const int row = mi * 16 + l15;
      const bf16x8 pa = *(const bf16x8*)(pb + ((row * 128 + (ks * 4 + l4) * 16) ^ ((row & 7) << 4)));
      #pragma unroll
      for (int ni = 0; ni < 4; ni++)
        o[mi][ni] = __builtin_amdgcn_mfma_f32_16x16x32_bf16(pa, bv[ni], o[mi][ni], 0, 0, 0);
    }
  }

  // ---- epilogue: scale by 1/sum, bf16, replicate ----
  const int head = head_base + h;
  #pragma unroll
  for (int mi = 0; mi < 4; mi++)
    #pragma unroll
    for (int reg = 0; reg < 4; reg++) {
      const int p = mi * 16 + l4 * 4 + reg;
      if (p >= 49) continue;
      const float iv = inv[mi][reg];
      u16 hv[4];
      #pragma unroll
      for (int ni = 0; ni < 4; ni++) hv[ni] = f2bf(o[mi][ni][reg] * iv);
      for (int m = 0; m < rep; m++) {
        const size_t ob = ((size_t)b * 3136 + (size_t)(m * nreg + r) * 49 + p) * 768 + head * 64 + l15;
        #pragma unroll
        for (int ni = 0; ni < 4; ni++) fh[ob + ni * 16] = hv[ni];
      }
    }
}

__global__ __launch_bounds__(256)
void attn_all(const u16* __restrict__ qkv, const u16* __restrict__ g1,
              const u16* __restrict__ g2, u16* __restrict__ fh)
{
  __shared__ __align__(16) u16 sV[4][64 * 64];
  __shared__ __align__(16) u16 sP[4][64 * 64];
  const int tid = threadIdx.x;
  const int lane = tid & 63;
  const int w = tid >> 6;
  char* vb = (char*)sV[w];
  char* pb = (char*)sP[w];
  const int bid = blockIdx.x;

  if (bid < 1024) {
    attn_body<0>(qkv, fh, 8, 56, 0, 1,  bid * 4 + w,          lane, vb, pb);
  } else if (bid < 1280) {
    attn_body<1>(g1,  fh, 4, 28, 4, 4,  (bid - 1024) * 4 + w, lane, vb, pb);
  } else {
    attn_body<1>(g2,  fh, 2, 14, 8, 16, (bid - 1280) * 4 + w, lane, vb, pb);
  }
}

extern "C" void kernel_launch(void* const* d_in, const int* in_sizes, int n_in,
                              void* d_out, int out_size, void* d_ws, size_t ws_size,
                              hipStream_t stream)
{
  const float* x      = (const float*)d_in[0];
  const float* w_qkv  = (const float*)d_in[1];
  const float* w_proj = (const float*)d_in[2];
  const float* b_proj = (const float*)d_in[3];
  const float* c1w    = (const float*)d_in[4];
  const float* c1b    = (const float*)d_in[5];
  const float* c2w    = (const float*)d_in[6];
  const float* c2b    = (const float*)d_in[7];
  float* out = (float*)d_out;

  u16 *xh, *wqkvh, *wprojh, *qkvb, *g1, *g2, *fh;
  unsigned *wt1, *wt2;
  hipGetSymbolAddress((void**)&xh,     HIP_SYMBOL(g_xh));
  hipGetSymbolAddress((void**)&wqkvh,  HIP_SYMBOL(g_wqkvh));
  hipGetSymbolAddress((void**)&wprojh, HIP_SYMBOL(g_wprojh));
  hipGetSymbolAddress((void**)&qkvb,   HIP_SYMBOL(g_qkv));
  hipGetSymbolAddress((void**)&g1,     HIP_SYMBOL(g_g1));
  hipGetSymbolAddress((void**)&g2,     HIP_SYMBOL(g_g2));
  hipGetSymbolAddress((void**)&fh,     HIP_SYMBOL(g_fh));
  hipGetSymbolAddress((void**)&wt1,    HIP_SYMBOL(g_wt1));
  hipGetSymbolAddress((void**)&wt2,    HIP_SYMBOL(g_wt2));

  // 0) one-shot prep: conv weight f16-pair transpose + bf16 conversions
  prep_wt<<<18, 256, 0, stream>>>(c1w, wt1, c2w, wt2);
  cvt_bf16_3<<<2048, 256, 0, stream>>>(x, xh, 50176 * 768 / 4,
                                       w_qkv, wqkvh, 2304 * 768 / 4,
                                       w_proj, wprojh, 768 * 768 / 4);

  // 1) QKV GEMM: attn channels bf16, conv channels f16 (CF16 epilogue)
  gemm128<false, true, u16><<<(50176 / 128) * (2304 / 128), 256, 0, stream>>>(
      xh, wqkvh, nullptr, qkvb, 2304, 768, 2304 / 128);

  // 2) convs: f16 dot2 inner loop, branch-free load batches
  conv_s<1><<<dim3(48, 784), 256, 0, stream>>>(qkvb, wt1, c1b, g1, 256, 28);
  conv_s<2><<<dim3(48, 196), 256, 0, stream>>>(qkvb, wt2, c2b, g2, 512, 14);

  // 3) all three attention scales in one launch -> fused bf16
  attn_all<<<1024 + 256 + 64, 256, 0, stream>>>(qkvb, g1, g2, fh);

  // 4) proj GEMM + bias -> out (f32)
  gemm128<true, false, float><<<(50176 / 128) * (768 / 128), 256, 0, stream>>>(
      fh, wprojh, b_proj, out, 768, 768, 768 / 128);
}

// Round 17
// 517.388 us; speedup vs baseline: 1.3422x; 1.3422x over previous
//
#include <hip/hip_runtime.h>

typedef __attribute__((ext_vector_type(4))) float f32x4;
typedef __attribute__((ext_vector_type(8))) short bf16x8;
typedef __attribute__((ext_vector_type(4))) unsigned short u16x4;
typedef __attribute__((ext_vector_type(2))) unsigned int u32x2;
typedef __attribute__((ext_vector_type(2))) _Float16 h16x2;
typedef unsigned short u16;

#if defined(__has_builtin)
#if __has_builtin(__builtin_amdgcn_fdot2)
#define HAS_FDOT2 1
#endif
#endif

// Static device intermediates (BSS; fully rewritten every launch).
__device__ static u16   g_xh[(size_t)50176 * 768];     // bf16(x)            77 MB
__device__ static u16   g_wqkvh[(size_t)2304 * 768];   // bf16(w_qkv)       3.5 MB
__device__ static u16   g_wprojh[(size_t)768 * 768];   // bf16(w_proj)      1.2 MB
__device__ static u16   g_qkv[(size_t)50176 * 2304];   // qkv bf16/f16      231 MB
__device__ static u16   g_g1[(size_t)48 * 784 * 256];  // conv1 out bf16     19 MB
__device__ static u16   g_g2[(size_t)48 * 196 * 256];  // conv2 out bf16    4.8 MB
__device__ static u16   g_fh[(size_t)50176 * 768];     // fused bf16         77 MB
__device__ static unsigned g_wt1[18 * 256];            // conv1 w f16-pairs [18][256]
__device__ static unsigned g_wt2[18 * 256];            // conv2 w f16-pairs [18][256]

static __device__ __forceinline__ u16 f2bf(float x){
  unsigned u = __float_as_uint(x);
  u += 0x7fffu + ((u >> 16) & 1u);
  return (u16)(u >> 16);
}
static __device__ __forceinline__ float bf2f(u16 h){
  return __uint_as_float(((unsigned)h) << 16);
}
static __device__ __forceinline__ u16 f2h(float x){
  _Float16 h = (_Float16)x;
  u16 b; __builtin_memcpy(&b, &h, 2);
  return b;
}
static __device__ __forceinline__ h16x2 as_h2(unsigned u){
  h16x2 v; __builtin_memcpy(&v, &u, 4); return v;
}
static __device__ __forceinline__ float dot2(unsigned a, unsigned b, float c){
#ifdef HAS_FDOT2
  return __builtin_amdgcn_fdot2(as_h2(a), as_h2(b), c, false);
#else
  const h16x2 ha = as_h2(a), hb = as_h2(b);
  return c + (float)ha[0] * (float)hb[0] + (float)ha[1] * (float)hb[1];
#endif
}

// Merged f32 -> bf16 (RNE) for three arrays, vectorized x4, grid-stride.
__global__ __launch_bounds__(256)
void cvt_bf16_3(const float* __restrict__ i0, u16* __restrict__ o0, int n0,
                const float* __restrict__ i1, u16* __restrict__ o1, int n1,
                const float* __restrict__ i2, u16* __restrict__ o2, int n2)
{
  const int total = n0 + n1 + n2;
  int i = blockIdx.x * blockDim.x + threadIdx.x;
  const int stride = gridDim.x * blockDim.x;
  for (; i < total; i += stride) {
    const float* in; u16* out; int j = i;
    if (j < n0)           { in = i0; out = o0; }
    else if (j < n0 + n1) { in = i1; out = o1; j -= n0; }
    else                  { in = i2; out = o2; j -= n0 + n1; }
    const f32x4 v = ((const f32x4*)in)[j];
    u16x4 o;
    #pragma unroll
    for (int k = 0; k < 4; k++) o[k] = f2bf(v[k]);
    ((u16x4*)out)[j] = o;
  }
}

// Conv weight prep: [256ch][4ic][9tap] f32 -> [tap*2+k][256ch] packed f16
// pairs (ic 2k, 2k+1) for v_dot2.
__global__ __launch_bounds__(256)
void prep_wt(const float* __restrict__ w1, unsigned* __restrict__ wt1,
             const float* __restrict__ w2, unsigned* __restrict__ wt2)
{
  const int i = blockIdx.x * 256 + threadIdx.x;
  if (i < 4608) {
    const int ch = i & 255, t2 = i >> 8;     // t2 = tp*2+k, 0..17
    const int tp = t2 >> 1, k = t2 & 1;
    const int i0 = ch * 36 + (2 * k) * 9 + tp;
    const int i1 = ch * 36 + (2 * k + 1) * 9 + tp;
    wt1[t2 * 256 + ch] = (unsigned)f2h(w1[i0]) | ((unsigned)f2h(w1[i1]) << 16);
    wt2[t2 * 256 + ch] = (unsigned)f2h(w2[i0]) | ((unsigned)f2h(w2[i1]) << 16);
  }
}

// ---------------------------------------------------------------------------
// R6-verified 256x256-tile GEMM, 8 waves (2x4), BK=32, 4 LDS buffers,
// counted-vmcnt pipeline (lead-2, vmcnt(8), never drained in-loop).
// C = A * B^T (+bias).  Empirical session optimum (215-219 us QKV).
// CF16: write cols with (col%768)>=256 as f16 (conv input channels).
// ---------------------------------------------------------------------------
template<bool BIAS, bool CF16, typename OUT_T>
__global__ __launch_bounds__(512, 2)
void gemm256(const u16* __restrict__ A0, const u16* __restrict__ Bw,
             const float* __restrict__ bias, OUT_T* __restrict__ C,
             int N, int K, int GX)
{
  __shared__ __align__(16) char ldsb[4 * 32768];   // 4 buf x (A 16K + B 16K)
  const int tid = threadIdx.x;
  const int lane = tid & 63;
  const int w = tid >> 6;          // 0..7
  const int wm = w >> 2;           // 0..1 : row half (128 rows)
  const int wn = w & 3;            // 0..3 : col quarter (64 cols)
  const int l15 = lane & 15, l4 = lane >> 4;

  // T1 bijective XCD swizzle (m204).
  const int nwg = gridDim.x;
  const int bid = blockIdx.x;
  const int q8 = nwg >> 3, r8 = nwg & 7;
  const int xcd = bid & 7, lid = bid >> 3;
  const int swz = (xcd < r8 ? xcd * (q8 + 1) : r8 * (q8 + 1) + (xcd - r8) * q8) + lid;
  const int bn = swz % GX;
  const int bm = swz / GX;

  // ---- staging source precompute (inverse swizzle) ----
  const int sq = tid >> 3;                 // physical row within 64-row half
  const int sp = tid & 7;                  // physical chunk
  const int tt = sp ^ (sq & 7);
  const int sa = tt >> 2, scc = tt & 3;
  const int srow0 = sq * 2 + sa;           // logical row (half 0)
  const u16* a0 = A0 + (size_t)(bm * 256 + srow0) * K + scc * 8;
  const u16* a1 = A0 + (size_t)(bm * 256 + 128 + srow0) * K + scc * 8;
  const u16* b0 = Bw + (size_t)(bn * 256 + srow0) * K + scc * 8;
  const u16* b1 = Bw + (size_t)(bn * 256 + 128 + srow0) * K + scc * 8;
  const int wofs = w << 10;

  #define GLDS(srcp, ldsoff) __builtin_amdgcn_global_load_lds( \
      (__attribute__((address_space(1))) const void*)(srcp),   \
      (__attribute__((address_space(3))) void*)(ldsb + (ldsoff)), 16, 0, 0)

  auto STAGE = [&](int s) {
    const int bb = (s & 3) << 15;
    const int ko = s * 32;
    GLDS(a0 + ko, bb + wofs);
    GLDS(a1 + ko, bb + 8192 + wofs);
    GLDS(b0 + ko, bb + 16384 + wofs);
    GLDS(b1 + ko, bb + 24576 + wofs);
  };

  f32x4 acc[8][4];
  #pragma unroll
  for (int i = 0; i < 8; i++)
    #pragma unroll
    for (int j = 0; j < 4; j++) acc[i][j] = (f32x4)0.f;

  auto COMPUTE = [&](int t) {
    const char* base = ldsb + ((t & 3) << 15);
    bf16x8 bfr[4], afr[8];
    #pragma unroll
    for (int ni = 0; ni < 4; ni++) {
      const int r = wn * 64 + ni * 16 + l15;
      const int pr = r >> 1;
      const int p = (((r & 1) << 2) + l4) ^ (pr & 7);
      bfr[ni] = *(const bf16x8*)(base + 16384 + pr * 128 + p * 16);
    }
    #pragma unroll
    for (int mi = 0; mi < 8; mi++) {
      const int r = wm * 128 + mi * 16 + l15;
      const int pr = r >> 1;
      const int p = (((r & 1) << 2) + l4) ^ (pr & 7);
      afr[mi] = *(const bf16x8*)(base + pr * 128 + p * 16);
    }
    __builtin_amdgcn_s_setprio(1);
    #pragma unroll
    for (int mi = 0; mi < 8; mi++)
      #pragma unroll
      for (int ni = 0; ni < 4; ni++)
        acc[mi][ni] = __builtin_amdgcn_mfma_f32_16x16x32_bf16(afr[mi], bfr[ni], acc[mi][ni], 0, 0, 0);
    __builtin_amdgcn_s_setprio(0);
  };

  const int T = K >> 5;   // K/32 steps
  STAGE(0);
  STAGE(1);
  for (int t = 0; t < T - 2; ++t) {
    STAGE(t + 2);
    asm volatile("s_waitcnt vmcnt(8)" ::: "memory");
    __builtin_amdgcn_sched_barrier(0);
    __builtin_amdgcn_s_barrier();
    __builtin_amdgcn_sched_barrier(0);
    COMPUTE(t);
  }
  asm volatile("s_waitcnt vmcnt(4)" ::: "memory");
  __builtin_amdgcn_sched_barrier(0);
  __builtin_amdgcn_s_barrier();
  __builtin_amdgcn_sched_barrier(0);
  COMPUTE(T - 2);
  asm volatile("s_waitcnt vmcnt(0)" ::: "memory");
  __builtin_amdgcn_sched_barrier(0);
  __builtin_amdgcn_s_barrier();
  __builtin_amdgcn_sched_barrier(0);
  COMPUTE(T - 1);
  #undef GLDS

  // ---- epilogue ----
  #pragma unroll
  for (int mi = 0; mi < 8; mi++)
    #pragma unroll
    for (int ni = 0; ni < 4; ni++) {
      const int col = bn * 256 + wn * 64 + ni * 16 + l15;
      const float bv = BIAS ? bias[col] : 0.f;
      bool asf16 = false;
      if constexpr (CF16) {
        int cm = col;
        cm -= (cm >= 1536) ? 1536 : ((cm >= 768) ? 768 : 0);
        asf16 = (cm >= 256);
      }
      #pragma unroll
      for (int reg = 0; reg < 4; reg++) {
        const int row = bm * 256 + wm * 128 + mi * 16 + (l4 << 2) + reg;
        const float val = acc[mi][ni][reg] + bv;
        if constexpr (sizeof(OUT_T) == 2) {
          C[(size_t)row * N + col] = (OUT_T)(asf16 ? f2h(val) : f2bf(val));
        } else {
          C[(size_t)row * N + col] = val;
        }
      }
    }
}

// ---------------------------------------------------------------------------
// f16-dot2 grouped conv3x3 + bias + 2x2 maxpool -> bf16, NX=2: one thread =
// one output channel x TWO adjacent pooled outputs. 24 pixel loads + 18
// weight loads per 2 outputs (vs 16+18 per 1 in R15). Branch-free interior/
// boundary (wave-uniform); all-unconditional load batches. Live ~95 VGPR
// within __launch_bounds__(256,4)'s 128 budget.
// Patch: rows R0..R0+3S, cols C0..C0+5S; output x uses cols C0+2Sx..C0+(3+2x)S.
// ---------------------------------------------------------------------------
template<int S>
__global__ __launch_bounds__(256, 4)
void conv_s(const u16* __restrict__ qkv, const unsigned* __restrict__ wt,
            const float* __restrict__ bsrc, u16* __restrict__ gout,
            int chan0, int Pout)
{
  const int ch = threadIdx.x;          // output channel 0..255
  const int g = ch >> 2;
  const int bt = blockIdx.x;
  const int b = bt / 3, t = bt - b * 3;
  const int nxp = Pout >> 1;           // x-pairs per row
  const int blk = blockIdx.y;
  const int y = blk / nxp;
  const int x0 = (blk - y * nxp) * 2;

  // 18 packed f16 weight pairs -> registers (lane-coalesced loads).
  unsigned wp[18];
  #pragma unroll
  for (int j = 0; j < 18; j++) wp[j] = wt[j * 256 + ch];
  const float bv = bsrc[ch];

  const int R0 = 2 * S * y - S;
  const int C0 = 2 * S * x0 - S;
  const size_t basech = (size_t)t * 768 + chan0 + g * 4;
  const u16* const srcb = qkv + (size_t)b * 3136 * 2304 + basech;

  // pixel (i,c) -> two packed f16 pairs (4 input channels); 4 rows x 6 cols.
  u32x2 praw[4][6];
  const bool interior = (R0 >= 0) & (R0 + 3 * S < 56) & (C0 >= 0) & (C0 + 5 * S < 56);
  if (interior) {
    #pragma unroll
    for (int i = 0; i < 4; i++)
      #pragma unroll
      for (int c = 0; c < 6; c++)
        praw[i][c] = *(const u32x2*)&srcb[(size_t)((R0 + i * S) * 56 + C0 + c * S) * 2304];
  } else {
    #pragma unroll
    for (int i = 0; i < 4; i++) {
      const int iy = R0 + i * S;
      const int iyc = iy < 0 ? 0 : (iy > 55 ? 55 : iy);
      const bool rok = (iy >= 0) & (iy < 56);
      #pragma unroll
      for (int c = 0; c < 6; c++) {
        const int ix = C0 + c * S;
        const int ixc = ix < 0 ? 0 : (ix > 55 ? 55 : ix);
        u32x2 r2 = *(const u32x2*)&srcb[(size_t)(iyc * 56 + ixc) * 2304];
        const bool ok = rok & (ix >= 0) & (ix < 56);
        r2[0] = ok ? r2[0] : 0u;
        r2[1] = ok ? r2[1] : 0u;
        praw[i][c] = r2;
      }
    }
  }

  float acc[2][2][2];   // [x][dy][dx]
  #pragma unroll
  for (int x = 0; x < 2; x++)
    #pragma unroll
    for (int dy = 0; dy < 2; dy++)
      #pragma unroll
      for (int dx = 0; dx < 2; dx++) acc[x][dy][dx] = bv;

  #pragma unroll
  for (int i = 0; i < 4; i++)
    #pragma unroll
    for (int c = 0; c < 6; c++) {
      const u32x2 p2 = praw[i][c];
      #pragma unroll
      for (int dy = 0; dy < 2; dy++) {
        const int ky = i - dy;
        if (ky < 0 || ky > 2) continue;
        #pragma unroll
        for (int x = 0; x < 2; x++)
          #pragma unroll
          for (int dx = 0; dx < 2; dx++) {
            const int kx = c - 2 * x - dx;
            if (kx < 0 || kx > 2) continue;
            const int tp = ky * 3 + kx;
            acc[x][dy][dx] = dot2(p2[0], wp[tp * 2 + 0], acc[x][dy][dx]);
            acc[x][dy][dx] = dot2(p2[1], wp[tp * 2 + 1], acc[x][dy][dx]);
          }
      }
    }

  #pragma unroll
  for (int x = 0; x < 2; x++) {
    const float best = fmaxf(fmaxf(acc[x][0][0], acc[x][0][1]),
                             fmaxf(acc[x][1][0], acc[x][1][1]));
    gout[((size_t)bt * (Pout * Pout) + y * Pout + x0 + x) * 256 + ch] = f2bf(best);
  }
}

// ---------------------------------------------------------------------------
// MFMA windowed attention, ALL scales in one launch. One WAVE per
// (b, region, head); 4 waves/block.
// ---------------------------------------------------------------------------
template<int SRC>
static __device__ __forceinline__
void attn_body(const u16* __restrict__ src, u16* __restrict__ fh,
               int side, int Hs, int head_base, int rep,
               int unit, int lane, char* vb, char* pb)
{
  const int nreg = side * side;
  const int h = unit & 3; unit >>= 2;
  const int r = unit % nreg;
  const int b = unit / nreg;
  const int hr = r / side, wr = r - hr * side;
  const int l15 = lane & 15, l4 = lane >> 4;

  auto gidx = [&](int t, int pp, int c) -> size_t {
    const int py = pp / 7, px = pp - py * 7;
    const int yy = hr * 7 + py, xx = wr * 7 + px;
    if (SRC == 0) return ((size_t)(b * 3136 + yy * 56 + xx)) * 2304 + (size_t)(t * 768 + h * 64 + c);
    else          return ((size_t)(b * 3 + t)) * ((size_t)Hs * Hs * 256) + (size_t)(yy * Hs + xx) * 256 + h * 64 + c;
  };

  // ---- stage V (t=2), rows clamped; swizzle byte ^= ((q>>3)&3)<<5 ----
  for (int i = lane; i < 1024; i += 64) {
    const int q = i >> 4, dc = i & 15;
    const int qs = q > 48 ? 48 : q;
    const u16x4 v4 = *(const u16x4*)&src[gidx(2, qs, dc * 4)];
    *(u16x4*)(vb + ((q * 128 + dc * 8) ^ (((q >> 3) & 3) << 5))) = v4;
  }

  // ---- QK^T ----
  f32x4 s[4][4];
  #pragma unroll
  for (int i = 0; i < 4; i++)
    #pragma unroll
    for (int j = 0; j < 4; j++) s[i][j] = (f32x4)0.f;

  bf16x8 bk[4][2];
  #pragma unroll
  for (int ni = 0; ni < 4; ni++) {
    const int q = ni * 16 + l15;
    const int qs = q > 48 ? 48 : q;
    #pragma unroll
    for (int ks = 0; ks < 2; ks++)
      bk[ni][ks] = *(const bf16x8*)&src[gidx(1, qs, ks * 32 + l4 * 8)];
  }
  #pragma unroll
  for (int mi = 0; mi < 4; mi++) {
    const int p = mi * 16 + l15;
    const int ps = p > 48 ? 48 : p;
    const bf16x8 a0 = *(const bf16x8*)&src[gidx(0, ps, l4 * 8)];
    const bf16x8 a1 = *(const bf16x8*)&src[gidx(0, ps, 32 + l4 * 8)];
    #pragma unroll
    for (int ni = 0; ni < 4; ni++) {
      s[mi][ni] = __builtin_amdgcn_mfma_f32_16x16x32_bf16(a0, bk[ni][0], s[mi][ni], 0, 0, 0);
      s[mi][ni] = __builtin_amdgcn_mfma_f32_16x16x32_bf16(a1, bk[ni][1], s[mi][ni], 0, 0, 0);
    }
  }

  // ---- mask cols q>=49, in-register softmax (unnormalized P) ----
  #pragma unroll
  for (int ni = 0; ni < 4; ni++) {
    const bool bad = (ni * 16 + l15) > 48;
    #pragma unroll
    for (int mi = 0; mi < 4; mi++)
      #pragma unroll
      for (int reg = 0; reg < 4; reg++)
        s[mi][ni][reg] = bad ? -1e30f : s[mi][ni][reg];
  }

  float inv[4][4];
  #pragma unroll
  for (int mi = 0; mi < 4; mi++)
    #pragma unroll
    for (int reg = 0; reg < 4; reg++) {
      float m = fmaxf(fmaxf(s[mi][0][reg], s[mi][1][reg]), fmaxf(s[mi][2][reg], s[mi][3][reg]));
      m = fmaxf(m, __shfl_xor(m, 1));
      m = fmaxf(m, __shfl_xor(m, 2));
      m = fmaxf(m, __shfl_xor(m, 4));
      m = fmaxf(m, __shfl_xor(m, 8));
      float partial = 0.f;
      #pragma unroll
      for (int ni = 0; ni < 4; ni++) {
        const float e = __expf((s[mi][ni][reg] - m) * 0.125f);
        s[mi][ni][reg] = e;
        partial += e;
      }
      partial += __shfl_xor(partial, 1);
      partial += __shfl_xor(partial, 2);
      partial += __shfl_xor(partial, 4);
      partial += __shfl_xor(partial, 8);
      inv[mi][reg] = 1.f / partial;
    }

  // ---- P -> LDS (bf16, XOR-swizzled rows) ----
  #pragma unroll
  for (int mi = 0; mi < 4; mi++)
    #pragma unroll
    for (int ni = 0; ni < 4; ni++)
      #pragma unroll
      for (int reg = 0; reg < 4; reg++) {
        const int row = mi * 16 + l4 * 4 + reg;
        const int col = ni * 16 + l15;
        *(u16*)(pb + ((row * 128 + col * 2) ^ ((row & 7) << 4))) = f2bf(s[mi][ni][reg]);
      }
  __syncthreads();

  // ---- PV ----
  f32x4 o[4][4];
  #pragma unroll
  for (int i = 0; i < 4; i++)
    #pragma unroll
    for (int j = 0; j < 4; j++) o[i][j] = (f32x4)0.f;

  #pragma unroll
  for (int ks = 0; ks < 2; ks++) {
    bf16x8 bv[4];
    #pragma unroll
    for (int ni = 0; ni < 4; ni++)
      #pragma unroll
      for (int j = 0; j < 8; j++) {
        const int q = ks * 32 + l4 * 8 + j;
        bv[ni][j] = *(const short*)(vb + ((q * 128 + (ni * 16 + l15) * 2) ^ (((q >> 3) & 3) << 5)));
      }
    #pragma unroll
    for (int mi = 0; mi < 4; mi++) {
      const int row = mi * 16 + l15;
      const bf16x8 pa = *(const bf16x8*)(pb + ((row * 128 + (ks * 4 + l4) * 16) ^ ((row & 7) << 4)));
      #pragma unroll
      for (int ni = 0; ni < 4; ni++)
        o[mi][ni] = __builtin_amdgcn_mfma_f32_16x16x32_bf16(pa, bv[ni], o[mi][ni], 0, 0, 0);
    }
  }

  // ---- epilogue: scale by 1/sum, bf16, replicate ----
  const int head = head_base + h;
  #pragma unroll
  for (int mi = 0; mi < 4; mi++)
    #pragma unroll
    for (int reg = 0; reg < 4; reg++) {
      const int p = mi * 16 + l4 * 4 + reg;
      if (p >= 49) continue;
      const float iv = inv[mi][reg];
      u16 hv[4];
      #pragma unroll
      for (int ni = 0; ni < 4; ni++) hv[ni] = f2bf(o[mi][ni][reg] * iv);
      for (int m = 0; m < rep; m++) {
        const size_t ob = ((size_t)b * 3136 + (size_t)(m * nreg + r) * 49 + p) * 768 + head * 64 + l15;
        #pragma unroll
        for (int ni = 0; ni < 4; ni++) fh[ob + ni * 16] = hv[ni];
      }
    }
}

__global__ __launch_bounds__(256)
void attn_all(const u16* __restrict__ qkv, const u16* __restrict__ g1,
              const u16* __restrict__ g2, u16* __restrict__ fh)
{
  __shared__ __align__(16) u16 sV[4][64 * 64];
  __shared__ __align__(16) u16 sP[4][64 * 64];
  const int tid = threadIdx.x;
  const int lane = tid & 63;
  const int w = tid >> 6;
  char* vb = (char*)sV[w];
  char* pb = (char*)sP[w];
  const int bid = blockIdx.x;

  if (bid < 1024) {
    attn_body<0>(qkv, fh, 8, 56, 0, 1,  bid * 4 + w,          lane, vb, pb);
  } else if (bid < 1280) {
    attn_body<1>(g1,  fh, 4, 28, 4, 4,  (bid - 1024) * 4 + w, lane, vb, pb);
  } else {
    attn_body<1>(g2,  fh, 2, 14, 8, 16, (bid - 1280) * 4 + w, lane, vb, pb);
  }
}

extern "C" void kernel_launch(void* const* d_in, const int* in_sizes, int n_in,
                              void* d_out, int out_size, void* d_ws, size_t ws_size,
                              hipStream_t stream)
{
  const float* x      = (const float*)d_in[0];
  const float* w_qkv  = (const float*)d_in[1];
  const float* w_proj = (const float*)d_in[2];
  const float* b_proj = (const float*)d_in[3];
  const float* c1w    = (const float*)d_in[4];
  const float* c1b    = (const float*)d_in[5];
  const float* c2w    = (const float*)d_in[6];
  const float* c2b    = (const float*)d_in[7];
  float* out = (float*)d_out;

  u16 *xh, *wqkvh, *wprojh, *qkvb, *g1, *g2, *fh;
  unsigned *wt1, *wt2;
  hipGetSymbolAddress((void**)&xh,     HIP_SYMBOL(g_xh));
  hipGetSymbolAddress((void**)&wqkvh,  HIP_SYMBOL(g_wqkvh));
  hipGetSymbolAddress((void**)&wprojh, HIP_SYMBOL(g_wprojh));
  hipGetSymbolAddress((void**)&qkvb,   HIP_SYMBOL(g_qkv));
  hipGetSymbolAddress((void**)&g1,     HIP_SYMBOL(g_g1));
  hipGetSymbolAddress((void**)&g2,     HIP_SYMBOL(g_g2));
  hipGetSymbolAddress((void**)&fh,     HIP_SYMBOL(g_fh));
  hipGetSymbolAddress((void**)&wt1,    HIP_SYMBOL(g_wt1));
  hipGetSymbolAddress((void**)&wt2,    HIP_SYMBOL(g_wt2));

  // 0) one-shot prep: conv weight f16-pair transpose + bf16 conversions
  prep_wt<<<18, 256, 0, stream>>>(c1w, wt1, c2w, wt2);
  cvt_bf16_3<<<2048, 256, 0, stream>>>(x, xh, 50176 * 768 / 4,
                                       w_qkv, wqkvh, 2304 * 768 / 4,
                                       w_proj, wprojh, 768 * 768 / 4);

  // 1) QKV GEMM: attn channels bf16, conv channels f16 (CF16 epilogue)
  gemm256<false, true, u16><<<(50176 / 256) * (2304 / 256), 512, 0, stream>>>(
      xh, wqkvh, nullptr, qkvb, 2304, 768, 2304 / 256);

  // 2) convs: f16 dot2, NX=2 per thread, branch-free load batches
  conv_s<1><<<dim3(48, 28 * 14), 256, 0, stream>>>(qkvb, wt1, c1b, g1, 256, 28);
  conv_s<2><<<dim3(48, 14 * 7), 256, 0, stream>>>(qkvb, wt2, c2b, g2, 512, 14);

  // 3) all three attention scales in one launch -> fused bf16
  attn_all<<<1024 + 256 + 64, 256, 0, stream>>>(qkvb, g1, g2, fh);

  // 4) proj GEMM + bias -> out (f32)
  gemm256<true, false, float><<<(50176 / 256) * (768 / 256), 512, 0, stream>>>(
      fh, wprojh, b_proj, out, 768, 768, 768 / 256);
}

// Round 18
// 505.325 us; speedup vs baseline: 1.3742x; 1.0239x over previous
//
#include <hip/hip_runtime.h>

typedef __attribute__((ext_vector_type(4))) float f32x4;
typedef __attribute__((ext_vector_type(8))) short bf16x8;
typedef __attribute__((ext_vector_type(4))) unsigned short u16x4;
typedef __attribute__((ext_vector_type(2))) unsigned int u32x2;
typedef __attribute__((ext_vector_type(2))) _Float16 h16x2;
typedef unsigned short u16;

#if defined(__has_builtin)
#if __has_builtin(__builtin_amdgcn_fdot2)
#define HAS_FDOT2 1
#endif
#endif

// Static device intermediates (BSS; fully rewritten every launch).
__device__ static u16   g_xh[(size_t)50176 * 768];     // bf16(x)            77 MB
__device__ static u16   g_wqkvh[(size_t)2304 * 768];   // bf16(w_qkv)       3.5 MB
__device__ static u16   g_wprojh[(size_t)768 * 768];   // bf16(w_proj)      1.2 MB
__device__ static u16   g_qkv[(size_t)50176 * 2304];   // qkv bf16/f16      231 MB
__device__ static u16   g_g1[(size_t)48 * 784 * 256];  // conv1 out bf16     19 MB
__device__ static u16   g_g2[(size_t)48 * 196 * 256];  // conv2 out bf16    4.8 MB
__device__ static u16   g_fh[(size_t)50176 * 768];     // fused bf16         77 MB
__device__ static unsigned g_wt1[18 * 256];            // conv1 w f16-pairs [18][256]
__device__ static unsigned g_wt2[18 * 256];            // conv2 w f16-pairs [18][256]

static __device__ __forceinline__ u16 f2bf(float x){
  unsigned u = __float_as_uint(x);
  u += 0x7fffu + ((u >> 16) & 1u);
  return (u16)(u >> 16);
}
static __device__ __forceinline__ float bf2f(u16 h){
  return __uint_as_float(((unsigned)h) << 16);
}
static __device__ __forceinline__ u16 f2h(float x){
  _Float16 h = (_Float16)x;
  u16 b; __builtin_memcpy(&b, &h, 2);
  return b;
}
static __device__ __forceinline__ h16x2 as_h2(unsigned u){
  h16x2 v; __builtin_memcpy(&v, &u, 4); return v;
}
static __device__ __forceinline__ float dot2(unsigned a, unsigned b, float c){
#ifdef HAS_FDOT2
  return __builtin_amdgcn_fdot2(as_h2(a), as_h2(b), c, false);
#else
  const h16x2 ha = as_h2(a), hb = as_h2(b);
  return c + (float)ha[0] * (float)hb[0] + (float)ha[1] * (float)hb[1];
#endif
}

// Merged f32 -> bf16 (RNE) for three arrays, vectorized x4, grid-stride.
__global__ __launch_bounds__(256)
void cvt_bf16_3(const float* __restrict__ i0, u16* __restrict__ o0, int n0,
                const float* __restrict__ i1, u16* __restrict__ o1, int n1,
                const float* __restrict__ i2, u16* __restrict__ o2, int n2)
{
  const int total = n0 + n1 + n2;
  int i = blockIdx.x * blockDim.x + threadIdx.x;
  const int stride = gridDim.x * blockDim.x;
  for (; i < total; i += stride) {
    const float* in; u16* out; int j = i;
    if (j < n0)           { in = i0; out = o0; }
    else if (j < n0 + n1) { in = i1; out = o1; j -= n0; }
    else                  { in = i2; out = o2; j -= n0 + n1; }
    const f32x4 v = ((const f32x4*)in)[j];
    u16x4 o;
    #pragma unroll
    for (int k = 0; k < 4; k++) o[k] = f2bf(v[k]);
    ((u16x4*)out)[j] = o;
  }
}

// Conv weight prep: [256ch][4ic][9tap] f32 -> [tap*2+k][256ch] packed f16
// pairs (ic 2k, 2k+1) for v_dot2.
__global__ __launch_bounds__(256)
void prep_wt(const float* __restrict__ w1, unsigned* __restrict__ wt1,
             const float* __restrict__ w2, unsigned* __restrict__ wt2)
{
  const int i = blockIdx.x * 256 + threadIdx.x;
  if (i < 4608) {
    const int ch = i & 255, t2 = i >> 8;     // t2 = tp*2+k, 0..17
    const int tp = t2 >> 1, k = t2 & 1;
    const int i0 = ch * 36 + (2 * k) * 9 + tp;
    const int i1 = ch * 36 + (2 * k + 1) * 9 + tp;
    wt1[t2 * 256 + ch] = (unsigned)f2h(w1[i0]) | ((unsigned)f2h(w1[i1]) << 16);
    wt2[t2 * 256 + ch] = (unsigned)f2h(w2[i0]) | ((unsigned)f2h(w2[i1]) << 16);
  }
}

// ---------------------------------------------------------------------------
// R6-verified 256x256-tile GEMM, 8 waves (2x4), BK=32, 4 LDS buffers,
// counted-vmcnt pipeline (lead-2, vmcnt(8), never drained in-loop).
// C = A * B^T (+bias).  Empirical session optimum (215-219 us QKV).
// CF16: write cols with (col%768)>=256 as f16 (conv input channels).
// ---------------------------------------------------------------------------
template<bool BIAS, bool CF16, typename OUT_T>
__global__ __launch_bounds__(512, 2)
void gemm256(const u16* __restrict__ A0, const u16* __restrict__ Bw,
             const float* __restrict__ bias, OUT_T* __restrict__ C,
             int N, int K, int GX)
{
  __shared__ __align__(16) char ldsb[4 * 32768];   // 4 buf x (A 16K + B 16K)
  const int tid = threadIdx.x;
  const int lane = tid & 63;
  const int w = tid >> 6;          // 0..7
  const int wm = w >> 2;           // 0..1 : row half (128 rows)
  const int wn = w & 3;            // 0..3 : col quarter (64 cols)
  const int l15 = lane & 15, l4 = lane >> 4;

  // T1 bijective XCD swizzle (m204).
  const int nwg = gridDim.x;
  const int bid = blockIdx.x;
  const int q8 = nwg >> 3, r8 = nwg & 7;
  const int xcd = bid & 7, lid = bid >> 3;
  const int swz = (xcd < r8 ? xcd * (q8 + 1) : r8 * (q8 + 1) + (xcd - r8) * q8) + lid;
  const int bn = swz % GX;
  const int bm = swz / GX;

  // ---- staging source precompute (inverse swizzle) ----
  const int sq = tid >> 3;                 // physical row within 64-row half
  const int sp = tid & 7;                  // physical chunk
  const int tt = sp ^ (sq & 7);
  const int sa = tt >> 2, scc = tt & 3;
  const int srow0 = sq * 2 + sa;           // logical row (half 0)
  const u16* a0 = A0 + (size_t)(bm * 256 + srow0) * K + scc * 8;
  const u16* a1 = A0 + (size_t)(bm * 256 + 128 + srow0) * K + scc * 8;
  const u16* b0 = Bw + (size_t)(bn * 256 + srow0) * K + scc * 8;
  const u16* b1 = Bw + (size_t)(bn * 256 + 128 + srow0) * K + scc * 8;
  const int wofs = w << 10;

  #define GLDS(srcp, ldsoff) __builtin_amdgcn_global_load_lds( \
      (__attribute__((address_space(1))) const void*)(srcp),   \
      (__attribute__((address_space(3))) void*)(ldsb + (ldsoff)), 16, 0, 0)

  auto STAGE = [&](int s) {
    const int bb = (s & 3) << 15;
    const int ko = s * 32;
    GLDS(a0 + ko, bb + wofs);
    GLDS(a1 + ko, bb + 8192 + wofs);
    GLDS(b0 + ko, bb + 16384 + wofs);
    GLDS(b1 + ko, bb + 24576 + wofs);
  };

  f32x4 acc[8][4];
  #pragma unroll
  for (int i = 0; i < 8; i++)
    #pragma unroll
    for (int j = 0; j < 4; j++) acc[i][j] = (f32x4)0.f;

  auto COMPUTE = [&](int t) {
    const char* base = ldsb + ((t & 3) << 15);
    bf16x8 bfr[4], afr[8];
    #pragma unroll
    for (int ni = 0; ni < 4; ni++) {
      const int r = wn * 64 + ni * 16 + l15;
      const int pr = r >> 1;
      const int p = (((r & 1) << 2) + l4) ^ (pr & 7);
      bfr[ni] = *(const bf16x8*)(base + 16384 + pr * 128 + p * 16);
    }
    #pragma unroll
    for (int mi = 0; mi < 8; mi++) {
      const int r = wm * 128 + mi * 16 + l15;
      const int pr = r >> 1;
      const int p = (((r & 1) << 2) + l4) ^ (pr & 7);
      afr[mi] = *(const bf16x8*)(base + pr * 128 + p * 16);
    }
    __builtin_amdgcn_s_setprio(1);
    #pragma unroll
    for (int mi = 0; mi < 8; mi++)
      #pragma unroll
      for (int ni = 0; ni < 4; ni++)
        acc[mi][ni] = __builtin_amdgcn_mfma_f32_16x16x32_bf16(afr[mi], bfr[ni], acc[mi][ni], 0, 0, 0);
    __builtin_amdgcn_s_setprio(0);
  };

  const int T = K >> 5;   // K/32 steps
  STAGE(0);
  STAGE(1);
  for (int t = 0; t < T - 2; ++t) {
    STAGE(t + 2);
    asm volatile("s_waitcnt vmcnt(8)" ::: "memory");
    __builtin_amdgcn_sched_barrier(0);
    __builtin_amdgcn_s_barrier();
    __builtin_amdgcn_sched_barrier(0);
    COMPUTE(t);
  }
  asm volatile("s_waitcnt vmcnt(4)" ::: "memory");
  __builtin_amdgcn_sched_barrier(0);
  __builtin_amdgcn_s_barrier();
  __builtin_amdgcn_sched_barrier(0);
  COMPUTE(T - 2);
  asm volatile("s_waitcnt vmcnt(0)" ::: "memory");
  __builtin_amdgcn_sched_barrier(0);
  __builtin_amdgcn_s_barrier();
  __builtin_amdgcn_sched_barrier(0);
  COMPUTE(T - 1);
  #undef GLDS

  // ---- epilogue ----
  #pragma unroll
  for (int mi = 0; mi < 8; mi++)
    #pragma unroll
    for (int ni = 0; ni < 4; ni++) {
      const int col = bn * 256 + wn * 64 + ni * 16 + l15;
      const float bv = BIAS ? bias[col] : 0.f;
      bool asf16 = false;
      if constexpr (CF16) {
        int cm = col;
        cm -= (cm >= 1536) ? 1536 : ((cm >= 768) ? 768 : 0);
        asf16 = (cm >= 256);
      }
      #pragma unroll
      for (int reg = 0; reg < 4; reg++) {
        const int row = bm * 256 + wm * 128 + mi * 16 + (l4 << 2) + reg;
        const float val = acc[mi][ni][reg] + bv;
        if constexpr (sizeof(OUT_T) == 2) {
          C[(size_t)row * N + col] = (OUT_T)(asf16 ? f2h(val) : f2bf(val));
        } else {
          C[(size_t)row * N + col] = val;
        }
      }
    }
}

// ---------------------------------------------------------------------------
// f16-dot2 grouped conv3x3 + bias + 2x2 maxpool -> bf16, NX pooled outputs
// per thread (R17-verified NX=2 pattern, generalized). NC = 2*NX+2 patch
// cols. Branch-free interior/boundary (wave-uniform), unconditional load
// batches. NX=4/S=1: ~125 VGPR live -> __launch_bounds__(256,3) (168 budget).
// ---------------------------------------------------------------------------
template<int S, int NX, int MINW>
__global__ __launch_bounds__(256, MINW)
void conv_s(const u16* __restrict__ qkv, const unsigned* __restrict__ wt,
            const float* __restrict__ bsrc, u16* __restrict__ gout,
            int chan0, int Pout)
{
  constexpr int NC = 2 * NX + 2;
  const int ch = threadIdx.x;          // output channel 0..255
  const int g = ch >> 2;
  const int bt = blockIdx.x;
  const int b = bt / 3, t = bt - b * 3;
  const int nxp = Pout / NX;           // x-groups per row
  const int blk = blockIdx.y;
  const int y = blk / nxp;
  const int x0 = (blk - y * nxp) * NX;

  // 18 packed f16 weight pairs -> registers (lane-coalesced loads).
  unsigned wp[18];
  #pragma unroll
  for (int j = 0; j < 18; j++) wp[j] = wt[j * 256 + ch];
  const float bv = bsrc[ch];

  const int R0 = 2 * S * y - S;
  const int C0 = 2 * S * x0 - S;
  const size_t basech = (size_t)t * 768 + chan0 + g * 4;
  const u16* const srcb = qkv + (size_t)b * 3136 * 2304 + basech;

  // pixel (i,c) -> two packed f16 pairs (4 input channels); 4 rows x NC cols.
  u32x2 praw[4][NC];
  const bool interior = (R0 >= 0) & (R0 + 3 * S < 56) & (C0 >= 0) & (C0 + (NC - 1) * S < 56);
  if (interior) {
    #pragma unroll
    for (int i = 0; i < 4; i++)
      #pragma unroll
      for (int c = 0; c < NC; c++)
        praw[i][c] = *(const u32x2*)&srcb[(size_t)((R0 + i * S) * 56 + C0 + c * S) * 2304];
  } else {
    #pragma unroll
    for (int i = 0; i < 4; i++) {
      const int iy = R0 + i * S;
      const int iyc = iy < 0 ? 0 : (iy > 55 ? 55 : iy);
      const bool rok = (iy >= 0) & (iy < 56);
      #pragma unroll
      for (int c = 0; c < NC; c++) {
        const int ix = C0 + c * S;
        const int ixc = ix < 0 ? 0 : (ix > 55 ? 55 : ix);
        u32x2 r2 = *(const u32x2*)&srcb[(size_t)(iyc * 56 + ixc) * 2304];
        const bool ok = rok & (ix >= 0) & (ix < 56);
        r2[0] = ok ? r2[0] : 0u;
        r2[1] = ok ? r2[1] : 0u;
        praw[i][c] = r2;
      }
    }
  }

  float acc[NX][2][2];   // [x][dy][dx]
  #pragma unroll
  for (int x = 0; x < NX; x++)
    #pragma unroll
    for (int dy = 0; dy < 2; dy++)
      #pragma unroll
      for (int dx = 0; dx < 2; dx++) acc[x][dy][dx] = bv;

  #pragma unroll
  for (int i = 0; i < 4; i++)
    #pragma unroll
    for (int c = 0; c < NC; c++) {
      const u32x2 p2 = praw[i][c];
      #pragma unroll
      for (int dy = 0; dy < 2; dy++) {
        const int ky = i - dy;
        if (ky < 0 || ky > 2) continue;
        #pragma unroll
        for (int x = 0; x < NX; x++)
          #pragma unroll
          for (int dx = 0; dx < 2; dx++) {
            const int kx = c - 2 * x - dx;
            if (kx < 0 || kx > 2) continue;
            const int tp = ky * 3 + kx;
            acc[x][dy][dx] = dot2(p2[0], wp[tp * 2 + 0], acc[x][dy][dx]);
            acc[x][dy][dx] = dot2(p2[1], wp[tp * 2 + 1], acc[x][dy][dx]);
          }
      }
    }

  #pragma unroll
  for (int x = 0; x < NX; x++) {
    const float best = fmaxf(fmaxf(acc[x][0][0], acc[x][0][1]),
                             fmaxf(acc[x][1][0], acc[x][1][1]));
    gout[((size_t)bt * (Pout * Pout) + y * Pout + x0 + x) * 256 + ch] = f2bf(best);
  }
}

// ---------------------------------------------------------------------------
// MFMA windowed attention, ALL scales in one launch. One WAVE per
// (b, region, head); 4 waves/block.
// ---------------------------------------------------------------------------
template<int SRC>
static __device__ __forceinline__
void attn_body(const u16* __restrict__ src, u16* __restrict__ fh,
               int side, int Hs, int head_base, int rep,
               int unit, int lane, char* vb, char* pb)
{
  const int nreg = side * side;
  const int h = unit & 3; unit >>= 2;
  const int r = unit % nreg;
  const int b = unit / nreg;
  const int hr = r / side, wr = r - hr * side;
  const int l15 = lane & 15, l4 = lane >> 4;

  auto gidx = [&](int t, int pp, int c) -> size_t {
    const int py = pp / 7, px = pp - py * 7;
    const int yy = hr * 7 + py, xx = wr * 7 + px;
    if (SRC == 0) return ((size_t)(b * 3136 + yy * 56 + xx)) * 2304 + (size_t)(t * 768 + h * 64 + c);
    else          return ((size_t)(b * 3 + t)) * ((size_t)Hs * Hs * 256) + (size_t)(yy * Hs + xx) * 256 + h * 64 + c;
  };

  // ---- stage V (t=2), rows clamped; swizzle byte ^= ((q>>3)&3)<<5 ----
  for (int i = lane; i < 1024; i += 64) {
    const int q = i >> 4, dc = i & 15;
    const int qs = q > 48 ? 48 : q;
    const u16x4 v4 = *(const u16x4*)&src[gidx(2, qs, dc * 4)];
    *(u16x4*)(vb + ((q * 128 + dc * 8) ^ (((q >> 3) & 3) << 5))) = v4;
  }

  // ---- QK^T ----
  f32x4 s[4][4];
  #pragma unroll
  for (int i = 0; i < 4; i++)
    #pragma unroll
    for (int j = 0; j < 4; j++) s[i][j] = (f32x4)0.f;

  bf16x8 bk[4][2];
  #pragma unroll
  for (int ni = 0; ni < 4; ni++) {
    const int q = ni * 16 + l15;
    const int qs = q > 48 ? 48 : q;
    #pragma unroll
    for (int ks = 0; ks < 2; ks++)
      bk[ni][ks] = *(const bf16x8*)&src[gidx(1, qs, ks * 32 + l4 * 8)];
  }
  #pragma unroll
  for (int mi = 0; mi < 4; mi++) {
    const int p = mi * 16 + l15;
    const int ps = p > 48 ? 48 : p;
    const bf16x8 a0 = *(const bf16x8*)&src[gidx(0, ps, l4 * 8)];
    const bf16x8 a1 = *(const bf16x8*)&src[gidx(0, ps, 32 + l4 * 8)];
    #pragma unroll
    for (int ni = 0; ni < 4; ni++) {
      s[mi][ni] = __builtin_amdgcn_mfma_f32_16x16x32_bf16(a0, bk[ni][0], s[mi][ni], 0, 0, 0);
      s[mi][ni] = __builtin_amdgcn_mfma_f32_16x16x32_bf16(a1, bk[ni][1], s[mi][ni], 0, 0, 0);
    }
  }

  // ---- mask cols q>=49, in-register softmax (unnormalized P) ----
  #pragma unroll
  for (int ni = 0; ni < 4; ni++) {
    const bool bad = (ni * 16 + l15) > 48;
    #pragma unroll
    for (int mi = 0; mi < 4; mi++)
      #pragma unroll
      for (int reg = 0; reg < 4; reg++)
        s[mi][ni][reg] = bad ? -1e30f : s[mi][ni][reg];
  }

  float inv[4][4];
  #pragma unroll
  for (int mi = 0; mi < 4; mi++)
    #pragma unroll
    for (int reg = 0; reg < 4; reg++) {
      float m = fmaxf(fmaxf(s[mi][0][reg], s[mi][1][reg]), fmaxf(s[mi][2][reg], s[mi][3][reg]));
      m = fmaxf(m, __shfl_xor(m, 1));
      m = fmaxf(m, __shfl_xor(m, 2));
      m = fmaxf(m, __shfl_xor(m, 4));
      m = fmaxf(m, __shfl_xor(m, 8));
      float partial = 0.f;
      #pragma unroll
      for (int ni = 0; ni < 4; ni++) {
        const float e = __expf((s[mi][ni][reg] - m) * 0.125f);
        s[mi][ni][reg] = e;
        partial += e;
      }
      partial += __shfl_xor(partial, 1);
      partial += __shfl_xor(partial, 2);
      partial += __shfl_xor(partial, 4);
      partial += __shfl_xor(partial, 8);
      inv[mi][reg] = 1.f / partial;
    }

  // ---- P -> LDS (bf16, XOR-swizzled rows) ----
  #pragma unroll
  for (int mi = 0; mi < 4; mi++)
    #pragma unroll
    for (int ni = 0; ni < 4; ni++)
      #pragma unroll
      for (int reg = 0; reg < 4; reg++) {
        const int row = mi * 16 + l4 * 4 + reg;
        const int col = ni * 16 + l15;
        *(u16*)(pb + ((row * 128 + col * 2) ^ ((row & 7) << 4))) = f2bf(s[mi][ni][reg]);
      }
  __syncthreads();

  // ---- PV ----
  f32x4 o[4][4];
  #pragma unroll
  for (int i = 0; i < 4; i++)
    #pragma unroll
    for (int j = 0; j < 4; j++) o[i][j] = (f32x4)0.f;

  #pragma unroll
  for (int ks = 0; ks < 2; ks++) {
    bf16x8 bv[4];
    #pragma unroll
    for (int ni = 0; ni < 4; ni++)
      #pragma unroll
      for (int j = 0; j < 8; j++) {
        const int q = ks * 32 + l4 * 8 + j;
        bv[ni][j] = *(const short*)(vb + ((q * 128 + (ni * 16 + l15) * 2) ^ (((q >> 3) & 3) << 5)));
      }
    #pragma unroll
    for (int mi = 0; mi < 4; mi++) {
      const int row = mi * 16 + l15;
      const bf16x8 pa = *(const bf16x8*)(pb + ((row * 128 + (ks * 4 + l4) * 16) ^ ((row & 7) << 4)));
      #pragma unroll
      for (int ni = 0; ni < 4; ni++)
        o[mi][ni] = __builtin_amdgcn_mfma_f32_16x16x32_bf16(pa, bv[ni], o[mi][ni], 0, 0, 0);
    }
  }

  // ---- epilogue: scale by 1/sum, bf16, replicate ----
  const int head = head_base + h;
  #pragma unroll
  for (int mi = 0; mi < 4; mi++)
    #pragma unroll
    for (int reg = 0; reg < 4; reg++) {
      const int p = mi * 16 + l4 * 4 + reg;
      if (p >= 49) continue;
      const float iv = inv[mi][reg];
      u16 hv[4];
      #pragma unroll
      for (int ni = 0; ni < 4; ni++) hv[ni] = f2bf(o[mi][ni][reg] * iv);
      for (int m = 0; m < rep; m++) {
        const size_t ob = ((size_t)b * 3136 + (size_t)(m * nreg + r) * 49 + p) * 768 + head * 64 + l15;
        #pragma unroll
        for (int ni = 0; ni < 4; ni++) fh[ob + ni * 16] = hv[ni];
      }
    }
}

__global__ __launch_bounds__(256)
void attn_all(const u16* __restrict__ qkv, const u16* __restrict__ g1,
              const u16* __restrict__ g2, u16* __restrict__ fh)
{
  __shared__ __align__(16) u16 sV[4][64 * 64];
  __shared__ __align__(16) u16 sP[4][64 * 64];
  const int tid = threadIdx.x;
  const int lane = tid & 63;
  const int w = tid >> 6;
  char* vb = (char*)sV[w];
  char* pb = (char*)sP[w];
  const int bid = blockIdx.x;

  if (bid < 1024) {
    attn_body<0>(qkv, fh, 8, 56, 0, 1,  bid * 4 + w,          lane, vb, pb);
  } else if (bid < 1280) {
    attn_body<1>(g1,  fh, 4, 28, 4, 4,  (bid - 1024) * 4 + w, lane, vb, pb);
  } else {
    attn_body<1>(g2,  fh, 2, 14, 8, 16, (bid - 1280) * 4 + w, lane, vb, pb);
  }
}

extern "C" void kernel_launch(void* const* d_in, const int* in_sizes, int n_in,
                              void* d_out, int out_size, void* d_ws, size_t ws_size,
                              hipStream_t stream)
{
  const float* x      = (const float*)d_in[0];
  const float* w_qkv  = (const float*)d_in[1];
  const float* w_proj = (const float*)d_in[2];
  const float* b_proj = (const float*)d_in[3];
  const float* c1w    = (const float*)d_in[4];
  const float* c1b    = (const float*)d_in[5];
  const float* c2w    = (const float*)d_in[6];
  const float* c2b    = (const float*)d_in[7];
  float* out = (float*)d_out;

  u16 *xh, *wqkvh, *wprojh, *qkvb, *g1, *g2, *fh;
  unsigned *wt1, *wt2;
  hipGetSymbolAddress((void**)&xh,     HIP_SYMBOL(g_xh));
  hipGetSymbolAddress((void**)&wqkvh,  HIP_SYMBOL(g_wqkvh));
  hipGetSymbolAddress((void**)&wprojh, HIP_SYMBOL(g_wprojh));
  hipGetSymbolAddress((void**)&qkvb,   HIP_SYMBOL(g_qkv));
  hipGetSymbolAddress((void**)&g1,     HIP_SYMBOL(g_g1));
  hipGetSymbolAddress((void**)&g2,     HIP_SYMBOL(g_g2));
  hipGetSymbolAddress((void**)&fh,     HIP_SYMBOL(g_fh));
  hipGetSymbolAddress((void**)&wt1,    HIP_SYMBOL(g_wt1));
  hipGetSymbolAddress((void**)&wt2,    HIP_SYMBOL(g_wt2));

  // 0) one-shot prep: conv weight f16-pair transpose + bf16 conversions
  prep_wt<<<18, 256, 0, stream>>>(c1w, wt1, c2w, wt2);
  cvt_bf16_3<<<2048, 256, 0, stream>>>(x, xh, 50176 * 768 / 4,
                                       w_qkv, wqkvh, 2304 * 768 / 4,
                                       w_proj, wprojh, 768 * 768 / 4);

  // 1) QKV GEMM: attn channels bf16, conv channels f16 (CF16 epilogue)
  gemm256<false, true, u16><<<(50176 / 256) * (2304 / 256), 512, 0, stream>>>(
      xh, wqkvh, nullptr, qkvb, 2304, 768, 2304 / 256);

  // 2) convs: f16 dot2; scale1 NX=4 (256,3), scale2 NX=2 (256,4)
  conv_s<1, 4, 3><<<dim3(48, 28 * 7), 256, 0, stream>>>(qkvb, wt1, c1b, g1, 256, 28);
  conv_s<2, 2, 4><<<dim3(48, 14 * 7), 256, 0, stream>>>(qkvb, wt2, c2b, g2, 512, 14);

  // 3) all three attention scales in one launch -> fused bf16
  attn_all<<<1024 + 256 + 64, 256, 0, stream>>>(qkvb, g1, g2, fh);

  // 4) proj GEMM + bias -> out (f32)
  gemm256<true, false, float><<<(50176 / 256) * (768 / 256), 512, 0, stream>>>(
      fh, wprojh, b_proj, out, 768, 768, 768 / 256);
}

// Round 21
// 504.579 us; speedup vs baseline: 1.3763x; 1.0015x over previous
//
#include <hip/hip_runtime.h>

typedef __attribute__((ext_vector_type(4))) float f32x4;
typedef __attribute__((ext_vector_type(8))) short bf16x8;
typedef __attribute__((ext_vector_type(4))) unsigned short u16x4;
typedef __attribute__((ext_vector_type(2))) unsigned int u32x2;
typedef __attribute__((ext_vector_type(2))) _Float16 h16x2;
typedef unsigned short u16;

#if defined(__has_builtin)
#if __has_builtin(__builtin_amdgcn_fdot2)
#define HAS_FDOT2 1
#endif
#endif

// Static device intermediates (BSS; fully rewritten every launch).
__device__ static u16   g_xh[(size_t)50176 * 768];     // bf16(x)            77 MB
__device__ static u16   g_wqkvh[(size_t)2304 * 768];   // bf16(w_qkv)       3.5 MB
__device__ static u16   g_wprojh[(size_t)768 * 768];   // bf16(w_proj)      1.2 MB
__device__ static u16   g_qkv[(size_t)50176 * 2304];   // qkv bf16/f16      231 MB
__device__ static u16   g_g1[(size_t)48 * 784 * 256];  // conv1 out bf16     19 MB
__device__ static u16   g_g2[(size_t)48 * 196 * 256];  // conv2 out bf16    4.8 MB
__device__ static u16   g_fh[(size_t)50176 * 768];     // fused bf16         77 MB
__device__ static unsigned g_wt1[18 * 256];            // conv1 w f16-pairs [18][256]
__device__ static unsigned g_wt2[18 * 256];            // conv2 w f16-pairs [18][256]

static __device__ __forceinline__ u16 f2bf(float x){
  unsigned u = __float_as_uint(x);
  u += 0x7fffu + ((u >> 16) & 1u);
  return (u16)(u >> 16);
}
static __device__ __forceinline__ float bf2f(u16 h){
  return __uint_as_float(((unsigned)h) << 16);
}
static __device__ __forceinline__ u16 f2h(float x){
  _Float16 h = (_Float16)x;
  u16 b; __builtin_memcpy(&b, &h, 2);
  return b;
}
static __device__ __forceinline__ h16x2 as_h2(unsigned u){
  h16x2 v; __builtin_memcpy(&v, &u, 4); return v;
}
static __device__ __forceinline__ float dot2(unsigned a, unsigned b, float c){
#ifdef HAS_FDOT2
  return __builtin_amdgcn_fdot2(as_h2(a), as_h2(b), c, false);
#else
  const h16x2 ha = as_h2(a), hb = as_h2(b);
  return c + (float)ha[0] * (float)hb[0] + (float)ha[1] * (float)hb[1];
#endif
}

// Merged f32 -> bf16 (RNE) for three arrays, vectorized x4, grid-stride.
__global__ __launch_bounds__(256)
void cvt_bf16_3(const float* __restrict__ i0, u16* __restrict__ o0, int n0,
                const float* __restrict__ i1, u16* __restrict__ o1, int n1,
                const float* __restrict__ i2, u16* __restrict__ o2, int n2)
{
  const int total = n0 + n1 + n2;
  int i = blockIdx.x * blockDim.x + threadIdx.x;
  const int stride = gridDim.x * blockDim.x;
  for (; i < total; i += stride) {
    const float* in; u16* out; int j = i;
    if (j < n0)           { in = i0; out = o0; }
    else if (j < n0 + n1) { in = i1; out = o1; j -= n0; }
    else                  { in = i2; out = o2; j -= n0 + n1; }
    const f32x4 v = ((const f32x4*)in)[j];
    u16x4 o;
    #pragma unroll
    for (int k = 0; k < 4; k++) o[k] = f2bf(v[k]);
    ((u16x4*)out)[j] = o;
  }
}

// Conv weight prep: [256ch][4ic][9tap] f32 -> [tap*2+k][256ch] packed f16
// pairs (ic 2k, 2k+1) for v_dot2.
__global__ __launch_bounds__(256)
void prep_wt(const float* __restrict__ w1, unsigned* __restrict__ wt1,
             const float* __restrict__ w2, unsigned* __restrict__ wt2)
{
  const int i = blockIdx.x * 256 + threadIdx.x;
  if (i < 4608) {
    const int ch = i & 255, t2 = i >> 8;     // t2 = tp*2+k, 0..17
    const int tp = t2 >> 1, k = t2 & 1;
    const int i0 = ch * 36 + (2 * k) * 9 + tp;
    const int i1 = ch * 36 + (2 * k + 1) * 9 + tp;
    wt1[t2 * 256 + ch] = (unsigned)f2h(w1[i0]) | ((unsigned)f2h(w1[i1]) << 16);
    wt2[t2 * 256 + ch] = (unsigned)f2h(w2[i0]) | ((unsigned)f2h(w2[i1]) << 16);
  }
}

// ---------------------------------------------------------------------------
// R6-verified 256x256-tile GEMM, 8 waves (2x4), BK=32, 4 LDS buffers,
// counted-vmcnt pipeline (lead-2, vmcnt(8), never drained in-loop).
// C = A * B^T (+bias).  Empirical session optimum (215-219 us QKV).
// CF16: write cols with (col%768)>=256 as f16 (conv input channels).
// ---------------------------------------------------------------------------
template<bool BIAS, bool CF16, typename OUT_T>
__global__ __launch_bounds__(512, 2)
void gemm256(const u16* __restrict__ A0, const u16* __restrict__ Bw,
             const float* __restrict__ bias, OUT_T* __restrict__ C,
             int N, int K, int GX)
{
  __shared__ __align__(16) char ldsb[4 * 32768];   // 4 buf x (A 16K + B 16K)
  const int tid = threadIdx.x;
  const int lane = tid & 63;
  const int w = tid >> 6;          // 0..7
  const int wm = w >> 2;           // 0..1 : row half (128 rows)
  const int wn = w & 3;            // 0..3 : col quarter (64 cols)
  const int l15 = lane & 15, l4 = lane >> 4;

  // T1 bijective XCD swizzle (m204).
  const int nwg = gridDim.x;
  const int bid = blockIdx.x;
  const int q8 = nwg >> 3, r8 = nwg & 7;
  const int xcd = bid & 7, lid = bid >> 3;
  const int swz = (xcd < r8 ? xcd * (q8 + 1) : r8 * (q8 + 1) + (xcd - r8) * q8) + lid;
  const int bn = swz % GX;
  const int bm = swz / GX;

  // ---- staging source precompute (inverse swizzle) ----
  const int sq = tid >> 3;                 // physical row within 64-row half
  const int sp = tid & 7;                  // physical chunk
  const int tt = sp ^ (sq & 7);
  const int sa = tt >> 2, scc = tt & 3;
  const int srow0 = sq * 2 + sa;           // logical row (half 0)
  const u16* a0 = A0 + (size_t)(bm * 256 + srow0) * K + scc * 8;
  const u16* a1 = A0 + (size_t)(bm * 256 + 128 + srow0) * K + scc * 8;
  const u16* b0 = Bw + (size_t)(bn * 256 + srow0) * K + scc * 8;
  const u16* b1 = Bw + (size_t)(bn * 256 + 128 + srow0) * K + scc * 8;
  const int wofs = w << 10;

  #define GLDS(srcp, ldsoff) __builtin_amdgcn_global_load_lds( \
      (__attribute__((address_space(1))) const void*)(srcp),   \
      (__attribute__((address_space(3))) void*)(ldsb + (ldsoff)), 16, 0, 0)

  auto STAGE = [&](int s) {
    const int bb = (s & 3) << 15;
    const int ko = s * 32;
    GLDS(a0 + ko, bb + wofs);
    GLDS(a1 + ko, bb + 8192 + wofs);
    GLDS(b0 + ko, bb + 16384 + wofs);
    GLDS(b1 + ko, bb + 24576 + wofs);
  };

  f32x4 acc[8][4];
  #pragma unroll
  for (int i = 0; i < 8; i++)
    #pragma unroll
    for (int j = 0; j < 4; j++) acc[i][j] = (f32x4)0.f;

  auto COMPUTE = [&](int t) {
    const char* base = ldsb + ((t & 3) << 15);
    bf16x8 bfr[4], afr[8];
    #pragma unroll
    for (int ni = 0; ni < 4; ni++) {
      const int r = wn * 64 + ni * 16 + l15;
      const int pr = r >> 1;
      const int p = (((r & 1) << 2) + l4) ^ (pr & 7);
      bfr[ni] = *(const bf16x8*)(base + 16384 + pr * 128 + p * 16);
    }
    #pragma unroll
    for (int mi = 0; mi < 8; mi++) {
      const int r = wm * 128 + mi * 16 + l15;
      const int pr = r >> 1;
      const int p = (((r & 1) << 2) + l4) ^ (pr & 7);
      afr[mi] = *(const bf16x8*)(base + pr * 128 + p * 16);
    }
    __builtin_amdgcn_s_setprio(1);
    #pragma unroll
    for (int mi = 0; mi < 8; mi++)
      #pragma unroll
      for (int ni = 0; ni < 4; ni++)
        acc[mi][ni] = __builtin_amdgcn_mfma_f32_16x16x32_bf16(afr[mi], bfr[ni], acc[mi][ni], 0, 0, 0);
    __builtin_amdgcn_s_setprio(0);
  };

  const int T = K >> 5;   // K/32 steps
  STAGE(0);
  STAGE(1);
  for (int t = 0; t < T - 2; ++t) {
    STAGE(t + 2);
    asm volatile("s_waitcnt vmcnt(8)" ::: "memory");
    __builtin_amdgcn_sched_barrier(0);
    __builtin_amdgcn_s_barrier();
    __builtin_amdgcn_sched_barrier(0);
    COMPUTE(t);
  }
  asm volatile("s_waitcnt vmcnt(4)" ::: "memory");
  __builtin_amdgcn_sched_barrier(0);
  __builtin_amdgcn_s_barrier();
  __builtin_amdgcn_sched_barrier(0);
  COMPUTE(T - 2);
  asm volatile("s_waitcnt vmcnt(0)" ::: "memory");
  __builtin_amdgcn_sched_barrier(0);
  __builtin_amdgcn_s_barrier();
  __builtin_amdgcn_sched_barrier(0);
  COMPUTE(T - 1);
  #undef GLDS

  // ---- epilogue ----
  #pragma unroll
  for (int mi = 0; mi < 8; mi++)
    #pragma unroll
    for (int ni = 0; ni < 4; ni++) {
      const int col = bn * 256 + wn * 64 + ni * 16 + l15;
      const float bv = BIAS ? bias[col] : 0.f;
      bool asf16 = false;
      if constexpr (CF16) {
        int cm = col;
        cm -= (cm >= 1536) ? 1536 : ((cm >= 768) ? 768 : 0);
        asf16 = (cm >= 256);
      }
      #pragma unroll
      for (int reg = 0; reg < 4; reg++) {
        const int row = bm * 256 + wm * 128 + mi * 16 + (l4 << 2) + reg;
        const float val = acc[mi][ni][reg] + bv;
        if constexpr (sizeof(OUT_T) == 2) {
          C[(size_t)row * N + col] = (OUT_T)(asf16 ? f2h(val) : f2bf(val));
        } else {
          C[(size_t)row * N + col] = val;
        }
      }
    }
}

// ---------------------------------------------------------------------------
// f16-dot2 grouped conv3x3 + bias + 2x2 maxpool -> bf16, NX pooled outputs
// per thread (R17-verified NX=2 pattern, generalized). NC = 2*NX+2 patch
// cols. Branch-free interior/boundary (wave-uniform), unconditional load
// batches. NX=4/S=1: ~125 VGPR live -> __launch_bounds__(256,3) (168 budget).
// ---------------------------------------------------------------------------
template<int S, int NX, int MINW>
__global__ __launch_bounds__(256, MINW)
void conv_s(const u16* __restrict__ qkv, const unsigned* __restrict__ wt,
            const float* __restrict__ bsrc, u16* __restrict__ gout,
            int chan0, int Pout)
{
  constexpr int NC = 2 * NX + 2;
  const int ch = threadIdx.x;          // output channel 0..255
  const int g = ch >> 2;
  const int bt = blockIdx.x;
  const int b = bt / 3, t = bt - b * 3;
  const int nxp = Pout / NX;           // x-groups per row
  const int blk = blockIdx.y;
  const int y = blk / nxp;
  const int x0 = (blk - y * nxp) * NX;

  // 18 packed f16 weight pairs -> registers (lane-coalesced loads).
  unsigned wp[18];
  #pragma unroll
  for (int j = 0; j < 18; j++) wp[j] = wt[j * 256 + ch];
  const float bv = bsrc[ch];

  const int R0 = 2 * S * y - S;
  const int C0 = 2 * S * x0 - S;
  const size_t basech = (size_t)t * 768 + chan0 + g * 4;
  const u16* const srcb = qkv + (size_t)b * 3136 * 2304 + basech;

  // pixel (i,c) -> two packed f16 pairs (4 input channels); 4 rows x NC cols.
  u32x2 praw[4][NC];
  const bool interior = (R0 >= 0) & (R0 + 3 * S < 56) & (C0 >= 0) & (C0 + (NC - 1) * S < 56);
  if (interior) {
    #pragma unroll
    for (int i = 0; i < 4; i++)
      #pragma unroll
      for (int c = 0; c < NC; c++)
        praw[i][c] = *(const u32x2*)&srcb[(size_t)((R0 + i * S) * 56 + C0 + c * S) * 2304];
  } else {
    #pragma unroll
    for (int i = 0; i < 4; i++) {
      const int iy = R0 + i * S;
      const int iyc = iy < 0 ? 0 : (iy > 55 ? 55 : iy);
      const bool rok = (iy >= 0) & (iy < 56);
      #pragma unroll
      for (int c = 0; c < NC; c++) {
        const int ix = C0 + c * S;
        const int ixc = ix < 0 ? 0 : (ix > 55 ? 55 : ix);
        u32x2 r2 = *(const u32x2*)&srcb[(size_t)(iyc * 56 + ixc) * 2304];
        const bool ok = rok & (ix >= 0) & (ix < 56);
        r2[0] = ok ? r2[0] : 0u;
        r2[1] = ok ? r2[1] : 0u;
        praw[i][c] = r2;
      }
    }
  }

  float acc[NX][2][2];   // [x][dy][dx]
  #pragma unroll
  for (int x = 0; x < NX; x++)
    #pragma unroll
    for (int dy = 0; dy < 2; dy++)
      #pragma unroll
      for (int dx = 0; dx < 2; dx++) acc[x][dy][dx] = bv;

  #pragma unroll
  for (int i = 0; i < 4; i++)
    #pragma unroll
    for (int c = 0; c < NC; c++) {
      const u32x2 p2 = praw[i][c];
      #pragma unroll
      for (int dy = 0; dy < 2; dy++) {
        const int ky = i - dy;
        if (ky < 0 || ky > 2) continue;
        #pragma unroll
        for (int x = 0; x < NX; x++)
          #pragma unroll
          for (int dx = 0; dx < 2; dx++) {
            const int kx = c - 2 * x - dx;
            if (kx < 0 || kx > 2) continue;
            const int tp = ky * 3 + kx;
            acc[x][dy][dx] = dot2(p2[0], wp[tp * 2 + 0], acc[x][dy][dx]);
            acc[x][dy][dx] = dot2(p2[1], wp[tp * 2 + 1], acc[x][dy][dx]);
          }
      }
    }

  #pragma unroll
  for (int x = 0; x < NX; x++) {
    const float best = fmaxf(fmaxf(acc[x][0][0], acc[x][0][1]),
                             fmaxf(acc[x][1][0], acc[x][1][1]));
    gout[((size_t)bt * (Pout * Pout) + y * Pout + x0 + x) * 256 + ch] = f2bf(best);
  }
}

// ---------------------------------------------------------------------------
// MFMA windowed attention, ALL scales in one launch. One WAVE per
// (b, region, head); 4 waves/block.
// ---------------------------------------------------------------------------
template<int SRC>
static __device__ __forceinline__
void attn_body(const u16* __restrict__ src, u16* __restrict__ fh,
               int side, int Hs, int head_base, int rep,
               int unit, int lane, char* vb, char* pb)
{
  const int nreg = side * side;
  const int h = unit & 3; unit >>= 2;
  const int r = unit % nreg;
  const int b = unit / nreg;
  const int hr = r / side, wr = r - hr * side;
  const int l15 = lane & 15, l4 = lane >> 4;

  auto gidx = [&](int t, int pp, int c) -> size_t {
    const int py = pp / 7, px = pp - py * 7;
    const int yy = hr * 7 + py, xx = wr * 7 + px;
    if (SRC == 0) return ((size_t)(b * 3136 + yy * 56 + xx)) * 2304 + (size_t)(t * 768 + h * 64 + c);
    else          return ((size_t)(b * 3 + t)) * ((size_t)Hs * Hs * 256) + (size_t)(yy * Hs + xx) * 256 + h * 64 + c;
  };

  // ---- stage V (t=2), rows clamped; swizzle byte ^= ((q>>3)&3)<<5 ----
  for (int i = lane; i < 1024; i += 64) {
    const int q = i >> 4, dc = i & 15;
    const int qs = q > 48 ? 48 : q;
    const u16x4 v4 = *(const u16x4*)&src[gidx(2, qs, dc * 4)];
    *(u16x4*)(vb + ((q * 128 + dc * 8) ^ (((q >> 3) & 3) << 5))) = v4;
  }

  // ---- QK^T ----
  f32x4 s[4][4];
  #pragma unroll
  for (int i = 0; i < 4; i++)
    #pragma unroll
    for (int j = 0; j < 4; j++) s[i][j] = (f32x4)0.f;

  bf16x8 bk[4][2];
  #pragma unroll
  for (int ni = 0; ni < 4; ni++) {
    const int q = ni * 16 + l15;
    const int qs = q > 48 ? 48 : q;
    #pragma unroll
    for (int ks = 0; ks < 2; ks++)
      bk[ni][ks] = *(const bf16x8*)&src[gidx(1, qs, ks * 32 + l4 * 8)];
  }
  #pragma unroll
  for (int mi = 0; mi < 4; mi++) {
    const int p = mi * 16 + l15;
    const int ps = p > 48 ? 48 : p;
    const bf16x8 a0 = *(const bf16x8*)&src[gidx(0, ps, l4 * 8)];
    const bf16x8 a1 = *(const bf16x8*)&src[gidx(0, ps, 32 + l4 * 8)];
    #pragma unroll
    for (int ni = 0; ni < 4; ni++) {
      s[mi][ni] = __builtin_amdgcn_mfma_f32_16x16x32_bf16(a0, bk[ni][0], s[mi][ni], 0, 0, 0);
      s[mi][ni] = __builtin_amdgcn_mfma_f32_16x16x32_bf16(a1, bk[ni][1], s[mi][ni], 0, 0, 0);
    }
  }

  // ---- mask cols q>=49, in-register softmax (unnormalized P) ----
  #pragma unroll
  for (int ni = 0; ni < 4; ni++) {
    const bool bad = (ni * 16 + l15) > 48;
    #pragma unroll
    for (int mi = 0; mi < 4; mi++)
      #pragma unroll
      for (int reg = 0; reg < 4; reg++)
        s[mi][ni][reg] = bad ? -1e30f : s[mi][ni][reg];
  }

  float inv[4][4];
  #pragma unroll
  for (int mi = 0; mi < 4; mi++)
    #pragma unroll
    for (int reg = 0; reg < 4; reg++) {
      float m = fmaxf(fmaxf(s[mi][0][reg], s[mi][1][reg]), fmaxf(s[mi][2][reg], s[mi][3][reg]));
      m = fmaxf(m, __shfl_xor(m, 1));
      m = fmaxf(m, __shfl_xor(m, 2));
      m = fmaxf(m, __shfl_xor(m, 4));
      m = fmaxf(m, __shfl_xor(m, 8));
      float partial = 0.f;
      #pragma unroll
      for (int ni = 0; ni < 4; ni++) {
        const float e = __expf((s[mi][ni][reg] - m) * 0.125f);
        s[mi][ni][reg] = e;
        partial += e;
      }
      partial += __shfl_xor(partial, 1);
      partial += __shfl_xor(partial, 2);
      partial += __shfl_xor(partial, 4);
      partial += __shfl_xor(partial, 8);
      inv[mi][reg] = 1.f / partial;
    }

  // ---- P -> LDS (bf16, XOR-swizzled rows) ----
  #pragma unroll
  for (int mi = 0; mi < 4; mi++)
    #pragma unroll
    for (int ni = 0; ni < 4; ni++)
      #pragma unroll
      for (int reg = 0; reg < 4; reg++) {
        const int row = mi * 16 + l4 * 4 + reg;
        const int col = ni * 16 + l15;
        *(u16*)(pb + ((row * 128 + col * 2) ^ ((row & 7) << 4))) = f2bf(s[mi][ni][reg]);
      }
  __syncthreads();

  // ---- PV ----
  f32x4 o[4][4];
  #pragma unroll
  for (int i = 0; i < 4; i++)
    #pragma unroll
    for (int j = 0; j < 4; j++) o[i][j] = (f32x4)0.f;

  #pragma unroll
  for (int ks = 0; ks < 2; ks++) {
    bf16x8 bv[4];
    #pragma unroll
    for (int ni = 0; ni < 4; ni++)
      #pragma unroll
      for (int j = 0; j < 8; j++) {
        const int q = ks * 32 + l4 * 8 + j;
        bv[ni][j] = *(const short*)(vb + ((q * 128 + (ni * 16 + l15) * 2) ^ (((q >> 3) & 3) << 5)));
      }
    #pragma unroll
    for (int mi = 0; mi < 4; mi++) {
      const int row = mi * 16 + l15;
      const bf16x8 pa = *(const bf16x8*)(pb + ((row * 128 + (ks * 4 + l4) * 16) ^ ((row & 7) << 4)));
      #pragma unroll
      for (int ni = 0; ni < 4; ni++)
        o[mi][ni] = __builtin_amdgcn_mfma_f32_16x16x32_bf16(pa, bv[ni], o[mi][ni], 0, 0, 0);
    }
  }

  // ---- epilogue: scale by 1/sum, bf16, replicate ----
  const int head = head_base + h;
  #pragma unroll
  for (int mi = 0; mi < 4; mi++)
    #pragma unroll
    for (int reg = 0; reg < 4; reg++) {
      const int p = mi * 16 + l4 * 4 + reg;
      if (p >= 49) continue;
      const float iv = inv[mi][reg];
      u16 hv[4];
      #pragma unroll
      for (int ni = 0; ni < 4; ni++) hv[ni] = f2bf(o[mi][ni][reg] * iv);
      for (int m = 0; m < rep; m++) {
        const size_t ob = ((size_t)b * 3136 + (size_t)(m * nreg + r) * 49 + p) * 768 + head * 64 + l15;
        #pragma unroll
        for (int ni = 0; ni < 4; ni++) fh[ob + ni * 16] = hv[ni];
      }
    }
}

__global__ __launch_bounds__(256)
void attn_all(const u16* __restrict__ qkv, const u16* __restrict__ g1,
              const u16* __restrict__ g2, u16* __restrict__ fh)
{
  __shared__ __align__(16) u16 sV[4][64 * 64];
  __shared__ __align__(16) u16 sP[4][64 * 64];
  const int tid = threadIdx.x;
  const int lane = tid & 63;
  const int w = tid >> 6;
  char* vb = (char*)sV[w];
  char* pb = (char*)sP[w];
  const int bid = blockIdx.x;

  if (bid < 1024) {
    attn_body<0>(qkv, fh, 8, 56, 0, 1,  bid * 4 + w,          lane, vb, pb);
  } else if (bid < 1280) {
    attn_body<1>(g1,  fh, 4, 28, 4, 4,  (bid - 1024) * 4 + w, lane, vb, pb);
  } else {
    attn_body<1>(g2,  fh, 2, 14, 8, 16, (bid - 1280) * 4 + w, lane, vb, pb);
  }
}

extern "C" void kernel_launch(void* const* d_in, const int* in_sizes, int n_in,
                              void* d_out, int out_size, void* d_ws, size_t ws_size,
                              hipStream_t stream)
{
  const float* x      = (const float*)d_in[0];
  const float* w_qkv  = (const float*)d_in[1];
  const float* w_proj = (const float*)d_in[2];
  const float* b_proj = (const float*)d_in[3];
  const float* c1w    = (const float*)d_in[4];
  const float* c1b    = (const float*)d_in[5];
  const float* c2w    = (const float*)d_in[6];
  const float* c2b    = (const float*)d_in[7];
  float* out = (float*)d_out;

  u16 *xh, *wqkvh, *wprojh, *qkvb, *g1, *g2, *fh;
  unsigned *wt1, *wt2;
  hipGetSymbolAddress((void**)&xh,     HIP_SYMBOL(g_xh));
  hipGetSymbolAddress((void**)&wqkvh,  HIP_SYMBOL(g_wqkvh));
  hipGetSymbolAddress((void**)&wprojh, HIP_SYMBOL(g_wprojh));
  hipGetSymbolAddress((void**)&qkvb,   HIP_SYMBOL(g_qkv));
  hipGetSymbolAddress((void**)&g1,     HIP_SYMBOL(g_g1));
  hipGetSymbolAddress((void**)&g2,     HIP_SYMBOL(g_g2));
  hipGetSymbolAddress((void**)&fh,     HIP_SYMBOL(g_fh));
  hipGetSymbolAddress((void**)&wt1,    HIP_SYMBOL(g_wt1));
  hipGetSymbolAddress((void**)&wt2,    HIP_SYMBOL(g_wt2));

  // 0) one-shot prep: conv weight f16-pair transpose + bf16 conversions
  prep_wt<<<18, 256, 0, stream>>>(c1w, wt1, c2w, wt2);
  cvt_bf16_3<<<2048, 256, 0, stream>>>(x, xh, 50176 * 768 / 4,
                                       w_qkv, wqkvh, 2304 * 768 / 4,
                                       w_proj, wprojh, 768 * 768 / 4);

  // 1) QKV GEMM: attn channels bf16, conv channels f16 (CF16 epilogue)
  gemm256<false, true, u16><<<(50176 / 256) * (2304 / 256), 512, 0, stream>>>(
      xh, wqkvh, nullptr, qkvb, 2304, 768, 2304 / 256);

  // 2) convs: f16 dot2; scale1 NX=4 (256,3), scale2 NX=2 (256,4)
  conv_s<1, 4, 3><<<dim3(48, 28 * 7), 256, 0, stream>>>(qkvb, wt1, c1b, g1, 256, 28);
  conv_s<2, 2, 4><<<dim3(48, 14 * 7), 256, 0, stream>>>(qkvb, wt2, c2b, g2, 512, 14);

  // 3) all three attention scales in one launch -> fused bf16
  attn_all<<<1024 + 256 + 64, 256, 0, stream>>>(qkvb, g1, g2, fh);

  // 4) proj GEMM + bias -> out (f32)
  gemm256<true, false, float><<<(50176 / 256) * (768 / 256), 512, 0, stream>>>(
      fh, wprojh, b_proj, out, 768, 768, 768 / 256);
}